// Round 12
// baseline (383.070 us; speedup 1.0000x reference)
//
#include <hip/hip_runtime.h>
#include <hip/hip_bf16.h>
#include <math.h>

#define HH 256
#define WW 256
#define NB 4
#define NC 128
#define C4 32

typedef __attribute__((ext_vector_type(8))) short short8v;
typedef __attribute__((ext_vector_type(4))) float float4v;
typedef unsigned short ushort_t;

__device__ __forceinline__ float gelu_f(float v) {
    return 0.5f * v * (1.0f + erff(v * 0.7071067811865476f));
}
__device__ __forceinline__ unsigned short f2bf(float x) {
    __hip_bfloat16 h = __float2bfloat16(x);
    return __builtin_bit_cast(unsigned short, h);
}
__device__ __forceinline__ float bf2f(unsigned short u) {
    return __uint_as_float(((unsigned)u) << 16);
}
__device__ __forceinline__ float bfe(short8v v, int j) {
    return bf2f((ushort_t)v[j]);
}

// ------------------------------------------- att_xy (NHWC bf16 out) ----
__global__ void attxy_kernel(const float* __restrict__ params,
                             const float* __restrict__ dww, const float* __restrict__ dwb,
                             const float* __restrict__ pww, const float* __restrict__ pwb,
                             ushort_t* __restrict__ att)   // att[pix][32] bf16
{
    __shared__ float P[2048];
    __shared__ float DW[288];
    __shared__ float PW[1024];
    for (int i = threadIdx.x; i < 2048; i += 256) P[i] = params[i];
    for (int i = threadIdx.x; i < 288;  i += 256) DW[i] = dww[i];
    for (int i = threadIdx.x; i < 1024; i += 256) PW[i] = pww[i];
    __syncthreads();
    const int idx = blockIdx.x * 256 + threadIdx.x;
    const int h = idx >> 8, w = idx & 255;

    int iy0[3], iy1[3], ix0[3], ix1[3];
    float fy[3], fx[3];
    bool vy[3], vx[3];
#pragma unroll
    for (int d = 0; d < 3; ++d) {
        int hh = h - 1 + d;
        vy[d] = (hh >= 0 && hh < HH);
        float cy = hh * (7.0f / 255.0f);
        int i0 = (int)floorf(cy); i0 = min(max(i0, 0), 7);
        iy0[d] = i0; iy1[d] = min(i0 + 1, 7); fy[d] = cy - (float)i0;
        int ww2 = w - 1 + d;
        vx[d] = (ww2 >= 0 && ww2 < WW);
        float cx = ww2 * (7.0f / 255.0f);
        int j0 = (int)floorf(cx); j0 = min(max(j0, 0), 7);
        ix0[d] = j0; ix1[d] = min(j0 + 1, 7); fx[d] = cx - (float)j0;
    }
    float g[32];
#pragma unroll
    for (int c = 0; c < 32; ++c) {
        float a = dwb[c];
        const float* Pc = P + c * 64;
#pragma unroll
        for (int dy = 0; dy < 3; ++dy) {
            if (!vy[dy]) continue;
#pragma unroll
            for (int dx = 0; dx < 3; ++dx) {
                if (!vx[dx]) continue;
                float p00 = Pc[iy0[dy] * 8 + ix0[dx]];
                float p01 = Pc[iy0[dy] * 8 + ix1[dx]];
                float p10 = Pc[iy1[dy] * 8 + ix0[dx]];
                float p11 = Pc[iy1[dy] * 8 + ix1[dx]];
                float pt = p00 + (p01 - p00) * fx[dx];
                float pb = p10 + (p11 - p10) * fx[dx];
                float p  = pt + (pb - pt) * fy[dy];
                a += DW[c * 9 + dy * 3 + dx] * p;
            }
        }
        g[c] = gelu_f(a);
    }
    ushort_t* ap = att + (size_t)idx * 32;
#pragma unroll
    for (int q = 0; q < 4; ++q) {
        short8v pk;
#pragma unroll
        for (int j = 0; j < 8; ++j) {
            const int co = q * 8 + j;
            float a = pwb[co];
#pragma unroll
            for (int c = 0; c < 32; ++c) a += PW[co * 32 + c] * g[c];
            pk[j] = (short)f2bf(a);
        }
        *(short8v*)(ap + q * 8) = pk;
    }
}

// ------------------------------------------------------------ att_zx/zy ----
__global__ void attz_kernel(const float* __restrict__ params_zx, const float* __restrict__ zx_dww,
                            const float* __restrict__ zx_dwb, const float* __restrict__ zx_pww,
                            const float* __restrict__ zx_pwb,
                            const float* __restrict__ params_zy, const float* __restrict__ zy_dww,
                            const float* __restrict__ zy_dwb, const float* __restrict__ zy_pww,
                            const float* __restrict__ zy_pwb,
                            float* __restrict__ att_zx, float* __restrict__ att_zy)
{
    const bool sel = (blockIdx.x != 0);
    const float* params = sel ? params_zy : params_zx;
    const float* dww = sel ? zy_dww : zx_dww;
    const float* dwb = sel ? zy_dwb : zx_dwb;
    const float* pww = sel ? zy_pww : zx_pww;
    const float* pwb = sel ? zy_pwb : zx_pwb;
    float* att = sel ? att_zy : att_zx;
    const int pos = threadIdx.x;
    float g[32];
#pragma unroll
    for (int c = 0; c < 32; ++c) {
        float a = dwb[c];
#pragma unroll
        for (int d = 0; d < 3; ++d) {
            int p = pos - 1 + d;
            if (p < 0 || p > 255) continue;
            float cz = p * (7.0f / 255.0f);
            int i0 = (int)floorf(cz); i0 = min(max(i0, 0), 7);
            int i1 = min(i0 + 1, 7);
            float f = cz - (float)i0;
            float pv = params[c * 8 + i0];
            pv += (params[c * 8 + i1] - pv) * f;
            a += dww[c * 3 + d] * pv;
        }
        g[c] = gelu_f(a);
    }
#pragma unroll
    for (int co = 0; co < 32; ++co) {
        float a = pwb[co];
#pragma unroll
        for (int ci = 0; ci < 32; ++ci) a += pww[co * 32 + ci] * g[ci];
        att[co * 256 + pos] = a;
    }
}

// -------------------------------------------- pw fp32 -> bf16 [co][ci] ----
__global__ void convert_pw_kernel(const float* __restrict__ pw, ushort_t* __restrict__ pwb16) {
    int i = blockIdx.x * 256 + threadIdx.x;
    pwb16[i] = f2bf(pw[i]);
}

// ---------------------------------- ldw dw weights -> bf16 [tap][128] ----
__global__ void convert_ldwdw_kernel(const float* __restrict__ dww, ushort_t* __restrict__ dwwT) {
    int i = blockIdx.x * 256 + threadIdx.x;
    if (i < 1152) {
        int c = i / 9, tap = i % 9;
        dwwT[tap * 128 + c] = f2bf(dww[i]);
    }
}

// ---------------------------------------------- K1a: ln1g (xn path) ----
// thread = 2 px. Pass A: stats + keep ch96..127; write xn[96..127] + g.
// Pass B: re-read ch0..95 (L2/L3-hot), normalize, write xn bf16 NHWC.
__global__ __launch_bounds__(256, 3) void ln1g_xn_kernel(
    const float* __restrict__ x,
    const float* __restrict__ n1w, const float* __restrict__ n1b,
    const float* __restrict__ pww, const float* __restrict__ pwb,
    ushort_t* __restrict__ g, ushort_t* __restrict__ xn)
{
    const int b  = blockIdx.x >> 7;
    const int h  = ((blockIdx.x & 127) << 1) | (threadIdx.x >> 7);
    const int wq = threadIdx.x & 127;
    const int pix = h * WW + wq * 2;
    const float* xp = x + (size_t)b * NC * 65536 + pix;

    float s1a = 0.f, s2a = 0.f, s1b = 0.f, s2b = 0.f;
    float x4a[32], x4b[32];
#pragma unroll
    for (int k = 0; k < 96; ++k) {
        float2 v = *(const float2*)(xp + (size_t)k * 65536);
        s1a += v.x; s2a += v.x * v.x;
        s1b += v.y; s2b += v.y * v.y;
    }
#pragma unroll
    for (int j = 0; j < 32; ++j) {
        float2 v = *(const float2*)(xp + (size_t)(96 + j) * 65536);
        x4a[j] = v.x; x4b[j] = v.y;
        s1a += v.x; s2a += v.x * v.x;
        s1b += v.y; s2b += v.y * v.y;
    }
    const float m0 = s1a * (1.f / 128.f);
    const float r0 = rsqrtf(s2a * (1.f / 128.f) - m0 * m0 + 1e-6f);
    const float m1 = s1b * (1.f / 128.f);
    const float r1 = rsqrtf(s2b * (1.f / 128.f) - m1 * m1 + 1e-6f);

#pragma unroll
    for (int j = 0; j < 32; ++j) {
        const float nw = n1w[96 + j], nb = n1b[96 + j];
        x4a[j] = (x4a[j] - m0) * r0 * nw + nb;
        x4b[j] = (x4b[j] - m1) * r1 * nw + nb;
    }
    ushort_t* xnp = xn + ((size_t)b * 65536 + pix) * 128;
    // xn ch 96..127 from registers
#pragma unroll
    for (int q = 0; q < 4; ++q) {
        short8v pa, pb;
#pragma unroll
        for (int j = 0; j < 8; ++j) {
            pa[j] = (short)f2bf(x4a[q * 8 + j]);
            pb[j] = (short)f2bf(x4b[q * 8 + j]);
        }
        *(short8v*)(xnp + 96 + q * 8) = pa;
        *(short8v*)(xnp + 128 + 96 + q * 8) = pb;
    }
    // g = gelu(pw(x4))
    ushort_t* gp = g + ((size_t)b * 65536 + pix) * 32;
#pragma unroll
    for (int q = 0; q < 4; ++q) {
        short8v pk;
#pragma unroll
        for (int j = 0; j < 8; ++j) {
            const int co = q * 8 + j;
            float a = pwb[co];
#pragma unroll
            for (int jj = 0; jj < 32; ++jj) a += pww[co * 32 + jj] * x4a[jj];
            pk[j] = (short)f2bf(gelu_f(a));
        }
        *(short8v*)(gp + q * 8) = pk;
    }
#pragma unroll
    for (int q = 0; q < 4; ++q) {
        short8v pk;
#pragma unroll
        for (int j = 0; j < 8; ++j) {
            const int co = q * 8 + j;
            float a = pwb[co];
#pragma unroll
            for (int jj = 0; jj < 32; ++jj) a += pww[co * 32 + jj] * x4b[jj];
            pk[j] = (short)f2bf(gelu_f(a));
        }
        *(short8v*)(gp + 32 + q * 8) = pk;
    }
    asm volatile("" ::: "memory");   // force pass-B reloads (don't keep 192 live)
    // ---- pass B: xn ch 0..95 ----
#pragma unroll
    for (int cb = 0; cb < 12; ++cb) {
        short8v pa, pb;
#pragma unroll
        for (int j = 0; j < 8; ++j) {
            const int c = cb * 8 + j;
            float2 v = *(const float2*)(xp + (size_t)c * 65536);
            const float nw = n1w[c], nb = n1b[c];
            pa[j] = (short)f2bf((v.x - m0) * r0 * nw + nb);
            pb[j] = (short)f2bf((v.y - m1) * r1 * nw + nb);
        }
        *(short8v*)(xnp + cb * 8) = pa;
        *(short8v*)(xnp + 128 + cb * 8) = pb;
    }
}

// ---------------------------------------------- K1b: ln1g (fallback) ----
__global__ __launch_bounds__(256, 3) void ln1g_kernel(
    const float* __restrict__ x,
    const float* __restrict__ n1w, const float* __restrict__ n1b,
    const float* __restrict__ pww, const float* __restrict__ pwb,
    ushort_t* __restrict__ g, float2* __restrict__ stats)
{
    const int b  = blockIdx.x >> 7;
    const int h  = ((blockIdx.x & 127) << 1) | (threadIdx.x >> 7);
    const int wq = threadIdx.x & 127;
    const int pix = h * WW + wq * 2;
    const float* xp = x + (size_t)b * NC * 65536 + pix;

    float s1a = 0.f, s2a = 0.f, s1b = 0.f, s2b = 0.f;
    float x4a[32], x4b[32];
#pragma unroll
    for (int k = 0; k < 96; ++k) {
        float2 v = *(const float2*)(xp + (size_t)k * 65536);
        s1a += v.x; s2a += v.x * v.x;
        s1b += v.y; s2b += v.y * v.y;
    }
#pragma unroll
    for (int j = 0; j < 32; ++j) {
        float2 v = *(const float2*)(xp + (size_t)(96 + j) * 65536);
        x4a[j] = v.x; x4b[j] = v.y;
        s1a += v.x; s2a += v.x * v.x;
        s1b += v.y; s2b += v.y * v.y;
    }
    const float m0 = s1a * (1.f / 128.f);
    const float r0 = rsqrtf(s2a * (1.f / 128.f) - m0 * m0 + 1e-6f);
    const float m1 = s1b * (1.f / 128.f);
    const float r1 = rsqrtf(s2b * (1.f / 128.f) - m1 * m1 + 1e-6f);
    *(float4*)(&stats[(size_t)b * 65536 + pix]) = float4{m0, r0, m1, r1};

#pragma unroll
    for (int j = 0; j < 32; ++j) {
        const float nw = n1w[96 + j], nb = n1b[96 + j];
        x4a[j] = (x4a[j] - m0) * r0 * nw + nb;
        x4b[j] = (x4b[j] - m1) * r1 * nw + nb;
    }
    ushort_t* gp = g + ((size_t)b * 65536 + pix) * 32;
#pragma unroll
    for (int q = 0; q < 4; ++q) {
        short8v pk;
#pragma unroll
        for (int j = 0; j < 8; ++j) {
            const int co = q * 8 + j;
            float a = pwb[co];
#pragma unroll
            for (int jj = 0; jj < 32; ++jj) a += pww[co * 32 + jj] * x4a[jj];
            pk[j] = (short)f2bf(gelu_f(a));
        }
        *(short8v*)(gp + q * 8) = pk;
    }
#pragma unroll
    for (int q = 0; q < 4; ++q) {
        short8v pk;
#pragma unroll
        for (int j = 0; j < 8; ++j) {
            const int co = q * 8 + j;
            float a = pwb[co];
#pragma unroll
            for (int jj = 0; jj < 32; ++jj) a += pww[co * 32 + jj] * x4b[jj];
            pk[j] = (short)f2bf(gelu_f(a));
        }
        *(short8v*)(gp + 32 + q * 8) = pk;
    }
}

// ---------------------------------------------- K2a: fuse (xn path) ----
// Block = 64-px strip; 256 thr = 4 q x 64 px. All activation reads bf16.
__global__ __launch_bounds__(256) void fuse_xn_kernel(
    const ushort_t* __restrict__ xn,
    const float* __restrict__ n2w, const float* __restrict__ n2b,
    const ushort_t* __restrict__ att_xy, const float* __restrict__ att_zx,
    const float* __restrict__ att_zy,
    const ushort_t* __restrict__ g,
    const float* __restrict__ dww, const float* __restrict__ dwb,
    ushort_t* __restrict__ z)
{
    __shared__ __align__(16) ushort_t gs[3][66][40];
    __shared__ float rs[4][64];
    __shared__ float rq[4][64];

    const int lid  = (blockIdx.x & 7) * 512 + (blockIdx.x >> 3);
    const int b     = lid >> 10;
    const int h     = (lid >> 2) & 255;
    const int strip = lid & 3;
    const int tid = threadIdx.x;
    const int q  = tid >> 6;
    const int px = tid & 63;
    const int w  = strip * 64 + px;
    const int pix = h * WW + w;
    const int w0g = strip * 64;

    // stage g[3][66][32]
    for (int i = tid; i < 792; i += 256) {
        const int row  = i / 264;
        const int rem  = i % 264;
        const int colc = rem >> 2;
        const int q8   = rem & 3;
        const int hy = min(max(h - 1 + row, 0), 255);
        const int cg = min(max(w0g + colc - 1, 0), 255);
        const short8v v = *(const short8v*)(g + ((size_t)b * 65536 + hy * WW + cg) * 32 + q8 * 8);
        *(short8v*)&gs[row][colc][q8 * 8] = v;
    }
    __syncthreads();

    const ushort_t* xnp = xn + ((size_t)b * 65536 + pix) * 128;
    const short8v xv0 = *(const short8v*)(xnp + q * 8);
    const short8v xv1 = *(const short8v*)(xnp + 32 + q * 8);
    const short8v xv2 = *(const short8v*)(xnp + 64 + q * 8);
    const short8v xv3 = *(const short8v*)(xnp + 96 + q * 8);
    const short8v av  = *(const short8v*)(att_xy + (size_t)pix * 32 + q * 8);

    float xnf[4][8], u[4][8];
#pragma unroll
    for (int j = 0; j < 8; ++j) {
        xnf[0][j] = bfe(xv0, j);
        xnf[1][j] = bfe(xv1, j);
        xnf[2][j] = bfe(xv2, j);
        xnf[3][j] = bfe(xv3, j);
        u[0][j] = xnf[0][j] * bfe(av, j);
        u[1][j] = xnf[1][j] * att_zx[(q * 8 + j) * 256 + h];   // wave-uniform
        u[2][j] = xnf[2][j] * att_zy[(q * 8 + j) * 256 + w];
    }
    // branch 3: dw3x3 over staged g
    {
        float a[8];
#pragma unroll
        for (int j = 0; j < 8; ++j) a[j] = dwb[q * 8 + j];
        const float ml = (w > 0) ? 1.f : 0.f;
        const float mr = (w < 255) ? 1.f : 0.f;
#pragma unroll
        for (int dy = -1; dy <= 1; ++dy) {
            int hy = h + dy;
            if (hy < 0 || hy > 255) continue;   // block-uniform
            const int rr = dy + 1;
            short8v gl = *(const short8v*)&gs[rr][px][q * 8];
            short8v gc = *(const short8v*)&gs[rr][px + 1][q * 8];
            short8v gv = *(const short8v*)&gs[rr][px + 2][q * 8];
            const int r0 = rr * 3;
#pragma unroll
            for (int j = 0; j < 8; ++j) {
                const float* wk = dww + (q * 8 + j) * 9 + r0;
                a[j] += (wk[0] * ml) * bfe(gl, j);
                a[j] += wk[1] * bfe(gc, j);
                a[j] += (wk[2] * mr) * bfe(gv, j);
            }
        }
#pragma unroll
        for (int j = 0; j < 8; ++j) u[3][j] = a[j];
    }
    // LN2 stats
    float e1 = 0.f, e2 = 0.f;
#pragma unroll
    for (int br = 0; br < 4; ++br)
#pragma unroll
        for (int j = 0; j < 8; ++j) { e1 += u[br][j]; e2 += u[br][j] * u[br][j]; }
    rs[q][px] = e1; rq[q][px] = e2;
    __syncthreads();
    const float ssum = rs[0][px] + rs[1][px] + rs[2][px] + rs[3][px];
    const float qsum = rq[0][px] + rq[1][px] + rq[2][px] + rq[3][px];
    const float m2 = ssum * (1.f / 128.f);
    const float r2 = rsqrtf(qsum * (1.f / 128.f) - m2 * m2 + 1e-6f);
    ushort_t* zp = z + ((size_t)b * 65536 + pix) * 128;
#pragma unroll
    for (int br = 0; br < 4; ++br) {
        short8v pk;
#pragma unroll
        for (int j = 0; j < 8; ++j) {
            const int c = br * 32 + q * 8 + j;
            pk[j] = (short)f2bf((u[br][j] - m2) * r2 * n2w[c] + n2b[c] + xnf[br][j]);
        }
        *(short8v*)(zp + br * 32 + q * 8) = pk;
    }
}

// ---------------------------------------------- K2b: fuse (fallback) ----
__global__ __launch_bounds__(256) void fuse_kernel(
    const float* __restrict__ x, const float2* __restrict__ stats,
    const float* __restrict__ n1w, const float* __restrict__ n1b,
    const float* __restrict__ n2w, const float* __restrict__ n2b,
    const ushort_t* __restrict__ att_xy, const float* __restrict__ att_zx,
    const float* __restrict__ att_zy,
    const ushort_t* __restrict__ g,
    const float* __restrict__ dww, const float* __restrict__ dwb,
    ushort_t* __restrict__ z)
{
    __shared__ __align__(16) ushort_t gs[3][66][40];
    __shared__ float rs[4][64];
    __shared__ float rq[4][64];

    const int lid  = (blockIdx.x & 7) * 512 + (blockIdx.x >> 3);
    const int b     = lid >> 10;
    const int h     = (lid >> 2) & 255;
    const int strip = lid & 3;
    const int tid = threadIdx.x;
    const int q  = tid >> 6;
    const int px = tid & 63;
    const int w  = strip * 64 + px;
    const int pix = h * WW + w;
    const int w0g = strip * 64;

    for (int i = tid; i < 792; i += 256) {
        const int row  = i / 264;
        const int rem  = i % 264;
        const int colc = rem >> 2;
        const int q8   = rem & 3;
        const int hy = min(max(h - 1 + row, 0), 255);
        const int cg = min(max(w0g + colc - 1, 0), 255);
        const short8v v = *(const short8v*)(g + ((size_t)b * 65536 + hy * WW + cg) * 32 + q8 * 8);
        *(short8v*)&gs[row][colc][q8 * 8] = v;
    }
    __syncthreads();

    const float2 st = stats[(size_t)b * 65536 + pix];
    const float m1 = st.x, r1 = st.y;

    float xn[4][8], u[4][8];
    {
        const short8v av = *(const short8v*)(att_xy + (size_t)pix * 32 + q * 8);
#pragma unroll
        for (int j = 0; j < 8; ++j) {
            const int c = q * 8 + j;
            float xv = x[((size_t)(b * NC + c)) * 65536 + pix];
            float v = (xv - m1) * r1 * n1w[c] + n1b[c];
            xn[0][j] = v; u[0][j] = v * bfe(av, j);
        }
    }
#pragma unroll
    for (int j = 0; j < 8; ++j) {
        const int c = 32 + q * 8 + j;
        float xv = x[((size_t)(b * NC + c)) * 65536 + pix];
        float v = (xv - m1) * r1 * n1w[c] + n1b[c];
        xn[1][j] = v; u[1][j] = v * att_zx[(c - 32) * 256 + h];
    }
#pragma unroll
    for (int j = 0; j < 8; ++j) {
        const int c = 64 + q * 8 + j;
        float xv = x[((size_t)(b * NC + c)) * 65536 + pix];
        float v = (xv - m1) * r1 * n1w[c] + n1b[c];
        xn[2][j] = v; u[2][j] = v * att_zy[(c - 64) * 256 + w];
    }
    {
        float a[8];
#pragma unroll
        for (int j = 0; j < 8; ++j) a[j] = dwb[q * 8 + j];
        const float ml = (w > 0) ? 1.f : 0.f;
        const float mr = (w < 255) ? 1.f : 0.f;
#pragma unroll
        for (int dy = -1; dy <= 1; ++dy) {
            int hy = h + dy;
            if (hy < 0 || hy > 255) continue;
            const int rr = dy + 1;
            short8v gl = *(const short8v*)&gs[rr][px][q * 8];
            short8v gc = *(const short8v*)&gs[rr][px + 1][q * 8];
            short8v gv = *(const short8v*)&gs[rr][px + 2][q * 8];
            const int r0 = rr * 3;
#pragma unroll
            for (int j = 0; j < 8; ++j) {
                const float* wk = dww + (q * 8 + j) * 9 + r0;
                a[j] += (wk[0] * ml) * bfe(gl, j);
                a[j] += wk[1] * bfe(gc, j);
                a[j] += (wk[2] * mr) * bfe(gv, j);
            }
        }
#pragma unroll
        for (int j = 0; j < 8; ++j) {
            const int c = 96 + q * 8 + j;
            float xv = x[((size_t)(b * NC + c)) * 65536 + pix];
            xn[3][j] = (xv - m1) * r1 * n1w[c] + n1b[c];
            u[3][j] = a[j];
        }
    }
    float e1 = 0.f, e2 = 0.f;
#pragma unroll
    for (int br = 0; br < 4; ++br)
#pragma unroll
        for (int j = 0; j < 8; ++j) { e1 += u[br][j]; e2 += u[br][j] * u[br][j]; }
    rs[q][px] = e1; rq[q][px] = e2;
    __syncthreads();
    const float ssum = rs[0][px] + rs[1][px] + rs[2][px] + rs[3][px];
    const float qsum = rq[0][px] + rq[1][px] + rq[2][px] + rq[3][px];
    const float m2 = ssum * (1.f / 128.f);
    const float r2 = rsqrtf(qsum * (1.f / 128.f) - m2 * m2 + 1e-6f);
    ushort_t* zp = z + ((size_t)b * 65536 + pix) * 128;
#pragma unroll
    for (int br = 0; br < 4; ++br) {
        short8v pk;
#pragma unroll
        for (int j = 0; j < 8; ++j) {
            const int c = br * 32 + q * 8 + j;
            pk[j] = (short)f2bf((u[br][j] - m2) * r2 * n2w[c] + n2b[c] + xn[br][j]);
        }
        *(short8v*)(zp + br * 32 + q * 8) = pk;
    }
}

// --------------------------------------------------------------- ldw ----
// R7-exact (LOCKED, 95 us measured R11): launch_bounds (256,3). (256,5)
// forces VGPR 84->48, rematerializes z loads (FETCH 54->293MB, 115->223us,
// R10). Px mapping it*16+pr is wave-contiguous; R8/R9 remaps inflated
// traffic 3-5x. Do not modify without counter evidence.
__global__ __launch_bounds__(256, 3) void ldw_kernel(
    const ushort_t* __restrict__ z, const ushort_t* __restrict__ dwwT,
    const float* __restrict__ dwb, const ushort_t* __restrict__ wb16,
    const float* __restrict__ pwb, float* __restrict__ out)
{
    __shared__ __align__(16) ushort_t tl[64 * 128];

    const int lid  = (blockIdx.x & 7) * 512 + (blockIdx.x >> 3);
    const int b    = lid >> 10;
    const int h    = (lid >> 2) & 255;
    const int px0  = (lid & 3) * 64;
    const int tid  = threadIdx.x;

    {
        const int oc = tid & 15;
        const int pr = tid >> 4;
        short8v wt[9];
#pragma unroll
        for (int t = 0; t < 9; ++t)
            wt[t] = *(const short8v*)(dwwT + t * 128 + oc * 8);
        const float4 bd0 = *(const float4*)(dwb + oc * 8);
        const float4 bd1 = *(const float4*)(dwb + oc * 8 + 4);
        const float bdw[8] = {bd0.x, bd0.y, bd0.z, bd0.w, bd1.x, bd1.y, bd1.z, bd1.w};
        char* tlb = (char*)tl;
#pragma unroll
        for (int it = 0; it < 4; ++it) {
            const int px = it * 16 + pr;
            const int w  = px0 + px;
            const int wl = (w > 0) ? w - 1 : 0;
            const int wr2 = (w < 255) ? w + 1 : 255;
            const float ml = (w > 0) ? 1.f : 0.f;
            const float mr = (w < 255) ? 1.f : 0.f;
            float a[8];
#pragma unroll
            for (int j = 0; j < 8; ++j) a[j] = bdw[j];
#pragma unroll
            for (int dy = -1; dy <= 1; ++dy) {
                int hy = h + dy;
                if (hy < 0 || hy > 255) continue;
                const ushort_t* zr = z + ((size_t)b * 65536 + hy * WW) * 128 + oc * 8;
                short8v vl = *(const short8v*)(zr + (size_t)wl * 128);
                short8v vc = *(const short8v*)(zr + (size_t)w * 128);
                short8v vr = *(const short8v*)(zr + (size_t)wr2 * 128);
                const int r0 = (dy + 1) * 3;
#pragma unroll
                for (int j = 0; j < 8; ++j) {
                    a[j] += (bfe(wt[r0], j) * ml) * bfe(vl, j);
                    a[j] += bfe(wt[r0 + 1], j) * bfe(vc, j);
                    a[j] += (bfe(wt[r0 + 2], j) * mr) * bfe(vr, j);
                }
            }
            short8v pk;
#pragma unroll
            for (int j = 0; j < 8; ++j) pk[j] = (short)f2bf(gelu_f(a[j]));
            const int chunk = oc ^ (px & 15);
            *(short8v*)(tlb + px * 256 + chunk * 16) = pk;
        }
    }
    __syncthreads();

    const int lane = tid & 63;
    const int wv   = tid >> 6;
    const int l15  = lane & 15;
    const int l4   = lane >> 4;

    short8v afrag[2][4];
#pragma unroll
    for (int ct = 0; ct < 2; ++ct) {
        const int co = wv * 32 + ct * 16 + l15;
#pragma unroll
        for (int ks = 0; ks < 4; ++ks)
            afrag[ct][ks] = *(const short8v*)(wb16 + co * 128 + ks * 32 + l4 * 8);
    }
    float4v bias[2];
#pragma unroll
    for (int ct = 0; ct < 2; ++ct) {
        const float4 bv = *(const float4*)(pwb + wv * 32 + ct * 16 + l4 * 4);
        bias[ct] = float4v{bv.x, bv.y, bv.z, bv.w};
    }

    const char* tlb = (const char*)tl;
#pragma unroll
    for (int pt = 0; pt < 4; ++pt) {
        const int px = pt * 16 + l15;
        short8v bfrag[4];
#pragma unroll
        for (int ks = 0; ks < 4; ++ks) {
            const int chunk = (ks * 4 + l4) ^ (px & 15);
            bfrag[ks] = *(const short8v*)(tlb + px * 256 + chunk * 16);
        }
        float4v acc0 = bias[0];
        float4v acc1 = bias[1];
#pragma unroll
        for (int ks = 0; ks < 4; ++ks) {
            acc0 = __builtin_amdgcn_mfma_f32_16x16x32_bf16(afrag[0][ks], bfrag[ks], acc0, 0, 0, 0);
            acc1 = __builtin_amdgcn_mfma_f32_16x16x32_bf16(afrag[1][ks], bfrag[ks], acc1, 0, 0, 0);
        }
#pragma unroll
        for (int ct = 0; ct < 2; ++ct) {
            const int co = wv * 32 + ct * 16 + l4 * 4;
            float* op = out + ((size_t)(b * NC + co)) * 65536 + h * WW + px0 + pt * 16 + l15;
            const float4v av = ct ? acc1 : acc0;
#pragma unroll
            for (int r = 0; r < 4; ++r) op[(size_t)r * 65536] = av[r];
        }
    }
}

// ------------------------------------------------------------- launch ----
extern "C" void kernel_launch(void* const* d_in, const int* in_sizes, int n_in,
                              void* d_out, int out_size, void* d_ws, size_t ws_size,
                              hipStream_t stream)
{
    (void)in_sizes; (void)n_in; (void)out_size;
    const float* x       = (const float*)d_in[0];
    const float* n1w     = (const float*)d_in[1];
    const float* n1b     = (const float*)d_in[2];
    const float* pxy     = (const float*)d_in[3];
    const float* cxy_dww = (const float*)d_in[4];
    const float* cxy_dwb = (const float*)d_in[5];
    const float* cxy_pww = (const float*)d_in[6];
    const float* cxy_pwb = (const float*)d_in[7];
    const float* pzx     = (const float*)d_in[8];
    const float* czx_dww = (const float*)d_in[9];
    const float* czx_dwb = (const float*)d_in[10];
    const float* czx_pww = (const float*)d_in[11];
    const float* czx_pwb = (const float*)d_in[12];
    const float* pzy     = (const float*)d_in[13];
    const float* czy_dww = (const float*)d_in[14];
    const float* czy_dwb = (const float*)d_in[15];
    const float* czy_pww = (const float*)d_in[16];
    const float* czy_pwb = (const float*)d_in[17];
    const float* dw_pww  = (const float*)d_in[18];
    const float* dw_pwb  = (const float*)d_in[19];
    const float* dw_dww  = (const float*)d_in[20];
    const float* dw_dwb  = (const float*)d_in[21];
    const float* n2w     = (const float*)d_in[22];
    const float* n2b     = (const float*)d_in[23];
    const float* ldw_dww = (const float*)d_in[24];
    const float* ldw_dwb = (const float*)d_in[25];
    const float* ldw_pww = (const float*)d_in[26];
    const float* ldw_pwb = (const float*)d_in[27];
    float* out = (float*)d_out;
    char* ws   = (char*)d_ws;

    // layout (bytes)
    ushort_t* att_xy = (ushort_t*)ws;                       // 4 MiB bf16 NHWC
    float* att_zx = (float*)(ws + 4194304);                 // 32 KB
    float* att_zy = att_zx + 32 * 256;                      // 32 KB
    ushort_t* pwb16 = (ushort_t*)(att_zy + 32 * 256);       // 32 KB
    ushort_t* dwwT  = pwb16 + 128 * 128;                    // 4 KB
    ushort_t* gbuf  = dwwT + 2048;                          // 16 MiB
    ushort_t* zbuf  = gbuf + (size_t)4 * 65536 * 32;        // 64 MiB
    char* tail      = (char*)(zbuf + (size_t)4 * 65536 * 128);
    const size_t base_bytes = (size_t)(tail - ws);
    const size_t xn_bytes = (size_t)4 * 65536 * 128 * 2;    // 64 MiB
    const bool use_xn = ws_size >= base_bytes + xn_bytes;

    attxy_kernel<<<256, 256, 0, stream>>>(pxy, cxy_dww, cxy_dwb, cxy_pww, cxy_pwb, att_xy);
    attz_kernel<<<2, 256, 0, stream>>>(pzx, czx_dww, czx_dwb, czx_pww, czx_pwb,
                                       pzy, czy_dww, czy_dwb, czy_pww, czy_pwb,
                                       att_zx, att_zy);
    convert_pw_kernel<<<64, 256, 0, stream>>>(ldw_pww, pwb16);
    convert_ldwdw_kernel<<<5, 256, 0, stream>>>(ldw_dww, dwwT);

    if (use_xn) {
        ushort_t* xnbuf = (ushort_t*)tail;
        ln1g_xn_kernel<<<512, 256, 0, stream>>>(x, n1w, n1b, dw_pww, dw_pwb, gbuf, xnbuf);
        fuse_xn_kernel<<<4096, 256, 0, stream>>>(xnbuf, n2w, n2b,
                                                 att_xy, att_zx, att_zy,
                                                 gbuf, dw_dww, dw_dwb, zbuf);
    } else {
        float2* stats = (float2*)tail;                      // 2 MiB
        ln1g_kernel<<<512, 256, 0, stream>>>(x, n1w, n1b, dw_pww, dw_pwb, gbuf, stats);
        fuse_kernel<<<4096, 256, 0, stream>>>(x, stats, n1w, n1b, n2w, n2b,
                                              att_xy, att_zx, att_zy,
                                              gbuf, dw_dww, dw_dwb, zbuf);
    }
    ldw_kernel<<<4096, 256, 0, stream>>>(zbuf, dwwT, ldw_dwb, pwb16, ldw_pwb, out);
}

// Round 13
// 281.157 us; speedup vs baseline: 1.3625x; 1.3625x over previous
//
#include <hip/hip_runtime.h>
#include <hip/hip_bf16.h>
#include <math.h>

#define HH 256
#define WW 256
#define NB 4
#define NC 128
#define C4 32

typedef __attribute__((ext_vector_type(8))) short short8v;
typedef __attribute__((ext_vector_type(4))) float float4v;
typedef unsigned short ushort_t;

__device__ __forceinline__ float gelu_f(float v) {
    return 0.5f * v * (1.0f + erff(v * 0.7071067811865476f));
}
__device__ __forceinline__ unsigned short f2bf(float x) {
    __hip_bfloat16 h = __float2bfloat16(x);
    return __builtin_bit_cast(unsigned short, h);
}
__device__ __forceinline__ float bf2f(unsigned short u) {
    return __uint_as_float(((unsigned)u) << 16);
}
__device__ __forceinline__ float bfe(short8v v, int j) {
    return bf2f((ushort_t)v[j]);
}

// ------------------------------------------- att_xy (NHWC bf16 out) ----
__global__ void attxy_kernel(const float* __restrict__ params,
                             const float* __restrict__ dww, const float* __restrict__ dwb,
                             const float* __restrict__ pww, const float* __restrict__ pwb,
                             ushort_t* __restrict__ att)   // att[pix][32] bf16
{
    __shared__ float P[2048];
    __shared__ float DW[288];
    __shared__ float PW[1024];
    for (int i = threadIdx.x; i < 2048; i += 256) P[i] = params[i];
    for (int i = threadIdx.x; i < 288;  i += 256) DW[i] = dww[i];
    for (int i = threadIdx.x; i < 1024; i += 256) PW[i] = pww[i];
    __syncthreads();
    const int idx = blockIdx.x * 256 + threadIdx.x;
    const int h = idx >> 8, w = idx & 255;

    int iy0[3], iy1[3], ix0[3], ix1[3];
    float fy[3], fx[3];
    bool vy[3], vx[3];
#pragma unroll
    for (int d = 0; d < 3; ++d) {
        int hh = h - 1 + d;
        vy[d] = (hh >= 0 && hh < HH);
        float cy = hh * (7.0f / 255.0f);
        int i0 = (int)floorf(cy); i0 = min(max(i0, 0), 7);
        iy0[d] = i0; iy1[d] = min(i0 + 1, 7); fy[d] = cy - (float)i0;
        int ww2 = w - 1 + d;
        vx[d] = (ww2 >= 0 && ww2 < WW);
        float cx = ww2 * (7.0f / 255.0f);
        int j0 = (int)floorf(cx); j0 = min(max(j0, 0), 7);
        ix0[d] = j0; ix1[d] = min(j0 + 1, 7); fx[d] = cx - (float)j0;
    }
    float g[32];
#pragma unroll
    for (int c = 0; c < 32; ++c) {
        float a = dwb[c];
        const float* Pc = P + c * 64;
#pragma unroll
        for (int dy = 0; dy < 3; ++dy) {
            if (!vy[dy]) continue;
#pragma unroll
            for (int dx = 0; dx < 3; ++dx) {
                if (!vx[dx]) continue;
                float p00 = Pc[iy0[dy] * 8 + ix0[dx]];
                float p01 = Pc[iy0[dy] * 8 + ix1[dx]];
                float p10 = Pc[iy1[dy] * 8 + ix0[dx]];
                float p11 = Pc[iy1[dy] * 8 + ix1[dx]];
                float pt = p00 + (p01 - p00) * fx[dx];
                float pb = p10 + (p11 - p10) * fx[dx];
                float p  = pt + (pb - pt) * fy[dy];
                a += DW[c * 9 + dy * 3 + dx] * p;
            }
        }
        g[c] = gelu_f(a);
    }
    ushort_t* ap = att + (size_t)idx * 32;
#pragma unroll
    for (int q = 0; q < 4; ++q) {
        short8v pk;
#pragma unroll
        for (int j = 0; j < 8; ++j) {
            const int co = q * 8 + j;
            float a = pwb[co];
#pragma unroll
            for (int c = 0; c < 32; ++c) a += PW[co * 32 + c] * g[c];
            pk[j] = (short)f2bf(a);
        }
        *(short8v*)(ap + q * 8) = pk;
    }
}

// ------------------------------------------------------------ att_zx/zy ----
__global__ void attz_kernel(const float* __restrict__ params_zx, const float* __restrict__ zx_dww,
                            const float* __restrict__ zx_dwb, const float* __restrict__ zx_pww,
                            const float* __restrict__ zx_pwb,
                            const float* __restrict__ params_zy, const float* __restrict__ zy_dww,
                            const float* __restrict__ zy_dwb, const float* __restrict__ zy_pww,
                            const float* __restrict__ zy_pwb,
                            float* __restrict__ att_zx, float* __restrict__ att_zy)
{
    const bool sel = (blockIdx.x != 0);
    const float* params = sel ? params_zy : params_zx;
    const float* dww = sel ? zy_dww : zx_dww;
    const float* dwb = sel ? zy_dwb : zx_dwb;
    const float* pww = sel ? zy_pww : zx_pww;
    const float* pwb = sel ? zy_pwb : zx_pwb;
    float* att = sel ? att_zy : att_zx;
    const int pos = threadIdx.x;
    float g[32];
#pragma unroll
    for (int c = 0; c < 32; ++c) {
        float a = dwb[c];
#pragma unroll
        for (int d = 0; d < 3; ++d) {
            int p = pos - 1 + d;
            if (p < 0 || p > 255) continue;
            float cz = p * (7.0f / 255.0f);
            int i0 = (int)floorf(cz); i0 = min(max(i0, 0), 7);
            int i1 = min(i0 + 1, 7);
            float f = cz - (float)i0;
            float pv = params[c * 8 + i0];
            pv += (params[c * 8 + i1] - pv) * f;
            a += dww[c * 3 + d] * pv;
        }
        g[c] = gelu_f(a);
    }
#pragma unroll
    for (int co = 0; co < 32; ++co) {
        float a = pwb[co];
#pragma unroll
        for (int ci = 0; ci < 32; ++ci) a += pww[co * 32 + ci] * g[ci];
        att[co * 256 + pos] = a;
    }
}

// -------------------------------------------- pw fp32 -> bf16 [co][ci] ----
__global__ void convert_pw_kernel(const float* __restrict__ pw, ushort_t* __restrict__ pwb16) {
    int i = blockIdx.x * 256 + threadIdx.x;
    pwb16[i] = f2bf(pw[i]);
}

// ---------------------------------- ldw dw weights -> bf16 [tap][128] ----
__global__ void convert_ldwdw_kernel(const float* __restrict__ dww, ushort_t* __restrict__ dwwT) {
    int i = blockIdx.x * 256 + threadIdx.x;
    if (i < 1152) {
        int c = i / 9, tap = i % 9;
        dwwT[tap * 128 + c] = f2bf(dww[i]);
    }
}

// ------------------------------------------------------------- K1: ln1g ----
// thread = 2 consecutive px (float2 loads). Block = 2 rows. Grid = 512.
__global__ __launch_bounds__(256, 3) void ln1g_kernel(
    const float* __restrict__ x,
    const float* __restrict__ n1w, const float* __restrict__ n1b,
    const float* __restrict__ pww, const float* __restrict__ pwb,
    ushort_t* __restrict__ g, float2* __restrict__ stats)
{
    const int b  = blockIdx.x >> 7;
    const int h  = ((blockIdx.x & 127) << 1) | (threadIdx.x >> 7);
    const int wq = threadIdx.x & 127;
    const int pix = h * WW + wq * 2;
    const float* xp = x + (size_t)b * NC * 65536 + pix;

    float s1a = 0.f, s2a = 0.f, s1b = 0.f, s2b = 0.f;
    float x4a[32], x4b[32];
#pragma unroll
    for (int k = 0; k < 96; ++k) {
        float2 v = *(const float2*)(xp + (size_t)k * 65536);
        s1a += v.x; s2a += v.x * v.x;
        s1b += v.y; s2b += v.y * v.y;
    }
#pragma unroll
    for (int j = 0; j < 32; ++j) {
        float2 v = *(const float2*)(xp + (size_t)(96 + j) * 65536);
        x4a[j] = v.x; x4b[j] = v.y;
        s1a += v.x; s2a += v.x * v.x;
        s1b += v.y; s2b += v.y * v.y;
    }
    const float m0 = s1a * (1.f / 128.f);
    const float r0 = rsqrtf(s2a * (1.f / 128.f) - m0 * m0 + 1e-6f);
    const float m1 = s1b * (1.f / 128.f);
    const float r1 = rsqrtf(s2b * (1.f / 128.f) - m1 * m1 + 1e-6f);
    *(float4*)(&stats[(size_t)b * 65536 + pix]) = float4{m0, r0, m1, r1};

#pragma unroll
    for (int j = 0; j < 32; ++j) {
        const float nw = n1w[96 + j], nb = n1b[96 + j];
        x4a[j] = (x4a[j] - m0) * r0 * nw + nb;
        x4b[j] = (x4b[j] - m1) * r1 * nw + nb;
    }
    ushort_t* gp = g + ((size_t)b * 65536 + pix) * 32;
#pragma unroll
    for (int q = 0; q < 4; ++q) {
        short8v pk;
#pragma unroll
        for (int j = 0; j < 8; ++j) {
            const int co = q * 8 + j;
            float a = pwb[co];
#pragma unroll
            for (int jj = 0; jj < 32; ++jj) a += pww[co * 32 + jj] * x4a[jj];
            pk[j] = (short)f2bf(gelu_f(a));
        }
        *(short8v*)(gp + q * 8) = pk;
    }
#pragma unroll
    for (int q = 0; q < 4; ++q) {
        short8v pk;
#pragma unroll
        for (int j = 0; j < 8; ++j) {
            const int co = q * 8 + j;
            float a = pwb[co];
#pragma unroll
            for (int jj = 0; jj < 32; ++jj) a += pww[co * 32 + jj] * x4b[jj];
            pk[j] = (short)f2bf(gelu_f(a));
        }
        *(short8v*)(gp + 32 + q * 8) = pk;
    }
}

// ------------------------------------------------------------- K2: fuse ----
// Block = 64-px strip; 256 thr = 4 q-groups x 64 px. g staged in LDS.
// R11-measured configuration (att_xy now bf16 — strictly less traffic).
__global__ __launch_bounds__(256) void fuse_kernel(
    const float* __restrict__ x, const float2* __restrict__ stats,
    const float* __restrict__ n1w, const float* __restrict__ n1b,
    const float* __restrict__ n2w, const float* __restrict__ n2b,
    const ushort_t* __restrict__ att_xy, const float* __restrict__ att_zx,
    const float* __restrict__ att_zy,
    const ushort_t* __restrict__ g,
    const float* __restrict__ dww, const float* __restrict__ dwb,
    ushort_t* __restrict__ z)
{
    __shared__ __align__(16) ushort_t gs[3][66][40];
    __shared__ float rs[4][64];
    __shared__ float rq[4][64];

    const int lid  = (blockIdx.x & 7) * 512 + (blockIdx.x >> 3);
    const int b     = lid >> 10;
    const int h     = (lid >> 2) & 255;
    const int strip = lid & 3;
    const int tid = threadIdx.x;
    const int q  = tid >> 6;
    const int px = tid & 63;
    const int w  = strip * 64 + px;
    const int pix = h * WW + w;
    const int w0g = strip * 64;

    for (int i = tid; i < 792; i += 256) {
        const int row  = i / 264;
        const int rem  = i % 264;
        const int colc = rem >> 2;
        const int q8   = rem & 3;
        const int hy = min(max(h - 1 + row, 0), 255);
        const int cg = min(max(w0g + colc - 1, 0), 255);
        const short8v v = *(const short8v*)(g + ((size_t)b * 65536 + hy * WW + cg) * 32 + q8 * 8);
        *(short8v*)&gs[row][colc][q8 * 8] = v;
    }
    __syncthreads();

    const float2 st = stats[(size_t)b * 65536 + pix];
    const float m1 = st.x, r1 = st.y;

    float xn[4][8], u[4][8];
    {
        const short8v av = *(const short8v*)(att_xy + (size_t)pix * 32 + q * 8);
#pragma unroll
        for (int j = 0; j < 8; ++j) {
            const int c = q * 8 + j;
            float xv = x[((size_t)(b * NC + c)) * 65536 + pix];
            float v = (xv - m1) * r1 * n1w[c] + n1b[c];
            xn[0][j] = v; u[0][j] = v * bfe(av, j);
        }
    }
#pragma unroll
    for (int j = 0; j < 8; ++j) {
        const int c = 32 + q * 8 + j;
        float xv = x[((size_t)(b * NC + c)) * 65536 + pix];
        float v = (xv - m1) * r1 * n1w[c] + n1b[c];
        xn[1][j] = v; u[1][j] = v * att_zx[(c - 32) * 256 + h];
    }
#pragma unroll
    for (int j = 0; j < 8; ++j) {
        const int c = 64 + q * 8 + j;
        float xv = x[((size_t)(b * NC + c)) * 65536 + pix];
        float v = (xv - m1) * r1 * n1w[c] + n1b[c];
        xn[2][j] = v; u[2][j] = v * att_zy[(c - 64) * 256 + w];
    }
    {
        float a[8];
#pragma unroll
        for (int j = 0; j < 8; ++j) a[j] = dwb[q * 8 + j];
        const float ml = (w > 0) ? 1.f : 0.f;
        const float mr = (w < 255) ? 1.f : 0.f;
#pragma unroll
        for (int dy = -1; dy <= 1; ++dy) {
            int hy = h + dy;
            if (hy < 0 || hy > 255) continue;
            const int rr = dy + 1;
            short8v gl = *(const short8v*)&gs[rr][px][q * 8];
            short8v gc = *(const short8v*)&gs[rr][px + 1][q * 8];
            short8v gv = *(const short8v*)&gs[rr][px + 2][q * 8];
            const int r0 = rr * 3;
#pragma unroll
            for (int j = 0; j < 8; ++j) {
                const float* wk = dww + (q * 8 + j) * 9 + r0;
                a[j] += (wk[0] * ml) * bfe(gl, j);
                a[j] += wk[1] * bfe(gc, j);
                a[j] += (wk[2] * mr) * bfe(gv, j);
            }
        }
#pragma unroll
        for (int j = 0; j < 8; ++j) {
            const int c = 96 + q * 8 + j;
            float xv = x[((size_t)(b * NC + c)) * 65536 + pix];
            xn[3][j] = (xv - m1) * r1 * n1w[c] + n1b[c];
            u[3][j] = a[j];
        }
    }
    float e1 = 0.f, e2 = 0.f;
#pragma unroll
    for (int br = 0; br < 4; ++br)
#pragma unroll
        for (int j = 0; j < 8; ++j) { e1 += u[br][j]; e2 += u[br][j] * u[br][j]; }
    rs[q][px] = e1; rq[q][px] = e2;
    __syncthreads();
    const float ssum = rs[0][px] + rs[1][px] + rs[2][px] + rs[3][px];
    const float qsum = rq[0][px] + rq[1][px] + rq[2][px] + rq[3][px];
    const float m2 = ssum * (1.f / 128.f);
    const float r2 = rsqrtf(qsum * (1.f / 128.f) - m2 * m2 + 1e-6f);
    ushort_t* zp = z + ((size_t)b * 65536 + pix) * 128;
#pragma unroll
    for (int br = 0; br < 4; ++br) {
        short8v pk;
#pragma unroll
        for (int j = 0; j < 8; ++j) {
            const int c = br * 32 + q * 8 + j;
            pk[j] = (short)f2bf((u[br][j] - m2) * r2 * n2w[c] + n2b[c] + xn[br][j]);
        }
        *(short8v*)(zp + br * 32 + q * 8) = pk;
    }
}

// --------------------------------------------------------------- ldw ----
// R7-exact (LOCKED, 95 us measured R11): launch_bounds (256,3). (256,5)
// forces VGPR 84->48, rematerializes z loads (FETCH 54->293MB, 115->223us,
// R10). Px mapping it*16+pr is wave-contiguous; R8/R9 remaps inflated
// traffic 3-5x. Do not modify without counter evidence.
__global__ __launch_bounds__(256, 3) void ldw_kernel(
    const ushort_t* __restrict__ z, const ushort_t* __restrict__ dwwT,
    const float* __restrict__ dwb, const ushort_t* __restrict__ wb16,
    const float* __restrict__ pwb, float* __restrict__ out)
{
    __shared__ __align__(16) ushort_t tl[64 * 128];

    const int lid  = (blockIdx.x & 7) * 512 + (blockIdx.x >> 3);
    const int b    = lid >> 10;
    const int h    = (lid >> 2) & 255;
    const int px0  = (lid & 3) * 64;
    const int tid  = threadIdx.x;

    {
        const int oc = tid & 15;
        const int pr = tid >> 4;
        short8v wt[9];
#pragma unroll
        for (int t = 0; t < 9; ++t)
            wt[t] = *(const short8v*)(dwwT + t * 128 + oc * 8);
        const float4 bd0 = *(const float4*)(dwb + oc * 8);
        const float4 bd1 = *(const float4*)(dwb + oc * 8 + 4);
        const float bdw[8] = {bd0.x, bd0.y, bd0.z, bd0.w, bd1.x, bd1.y, bd1.z, bd1.w};
        char* tlb = (char*)tl;
#pragma unroll
        for (int it = 0; it < 4; ++it) {
            const int px = it * 16 + pr;
            const int w  = px0 + px;
            const int wl = (w > 0) ? w - 1 : 0;
            const int wr2 = (w < 255) ? w + 1 : 255;
            const float ml = (w > 0) ? 1.f : 0.f;
            const float mr = (w < 255) ? 1.f : 0.f;
            float a[8];
#pragma unroll
            for (int j = 0; j < 8; ++j) a[j] = bdw[j];
#pragma unroll
            for (int dy = -1; dy <= 1; ++dy) {
                int hy = h + dy;
                if (hy < 0 || hy > 255) continue;
                const ushort_t* zr = z + ((size_t)b * 65536 + hy * WW) * 128 + oc * 8;
                short8v vl = *(const short8v*)(zr + (size_t)wl * 128);
                short8v vc = *(const short8v*)(zr + (size_t)w * 128);
                short8v vr = *(const short8v*)(zr + (size_t)wr2 * 128);
                const int r0 = (dy + 1) * 3;
#pragma unroll
                for (int j = 0; j < 8; ++j) {
                    a[j] += (bfe(wt[r0], j) * ml) * bfe(vl, j);
                    a[j] += bfe(wt[r0 + 1], j) * bfe(vc, j);
                    a[j] += (bfe(wt[r0 + 2], j) * mr) * bfe(vr, j);
                }
            }
            short8v pk;
#pragma unroll
            for (int j = 0; j < 8; ++j) pk[j] = (short)f2bf(gelu_f(a[j]));
            const int chunk = oc ^ (px & 15);
            *(short8v*)(tlb + px * 256 + chunk * 16) = pk;
        }
    }
    __syncthreads();

    const int lane = tid & 63;
    const int wv   = tid >> 6;
    const int l15  = lane & 15;
    const int l4   = lane >> 4;

    short8v afrag[2][4];
#pragma unroll
    for (int ct = 0; ct < 2; ++ct) {
        const int co = wv * 32 + ct * 16 + l15;
#pragma unroll
        for (int ks = 0; ks < 4; ++ks)
            afrag[ct][ks] = *(const short8v*)(wb16 + co * 128 + ks * 32 + l4 * 8);
    }
    float4v bias[2];
#pragma unroll
    for (int ct = 0; ct < 2; ++ct) {
        const float4 bv = *(const float4*)(pwb + wv * 32 + ct * 16 + l4 * 4);
        bias[ct] = float4v{bv.x, bv.y, bv.z, bv.w};
    }

    const char* tlb = (const char*)tl;
#pragma unroll
    for (int pt = 0; pt < 4; ++pt) {
        const int px = pt * 16 + l15;
        short8v bfrag[4];
#pragma unroll
        for (int ks = 0; ks < 4; ++ks) {
            const int chunk = (ks * 4 + l4) ^ (px & 15);
            bfrag[ks] = *(const short8v*)(tlb + px * 256 + chunk * 16);
        }
        float4v acc0 = bias[0];
        float4v acc1 = bias[1];
#pragma unroll
        for (int ks = 0; ks < 4; ++ks) {
            acc0 = __builtin_amdgcn_mfma_f32_16x16x32_bf16(afrag[0][ks], bfrag[ks], acc0, 0, 0, 0);
            acc1 = __builtin_amdgcn_mfma_f32_16x16x32_bf16(afrag[1][ks], bfrag[ks], acc1, 0, 0, 0);
        }
#pragma unroll
        for (int ct = 0; ct < 2; ++ct) {
            const int co = wv * 32 + ct * 16 + l4 * 4;
            float* op = out + ((size_t)(b * NC + co)) * 65536 + h * WW + px0 + pt * 16 + l15;
            const float4v av = ct ? acc1 : acc0;
#pragma unroll
            for (int r = 0; r < 4; ++r) op[(size_t)r * 65536] = av[r];
        }
    }
}

// ------------------------------------------------------------- launch ----
extern "C" void kernel_launch(void* const* d_in, const int* in_sizes, int n_in,
                              void* d_out, int out_size, void* d_ws, size_t ws_size,
                              hipStream_t stream)
{
    (void)in_sizes; (void)n_in; (void)out_size; (void)ws_size;
    const float* x       = (const float*)d_in[0];
    const float* n1w     = (const float*)d_in[1];
    const float* n1b     = (const float*)d_in[2];
    const float* pxy     = (const float*)d_in[3];
    const float* cxy_dww = (const float*)d_in[4];
    const float* cxy_dwb = (const float*)d_in[5];
    const float* cxy_pww = (const float*)d_in[6];
    const float* cxy_pwb = (const float*)d_in[7];
    const float* pzx     = (const float*)d_in[8];
    const float* czx_dww = (const float*)d_in[9];
    const float* czx_dwb = (const float*)d_in[10];
    const float* czx_pww = (const float*)d_in[11];
    const float* czx_pwb = (const float*)d_in[12];
    const float* pzy     = (const float*)d_in[13];
    const float* czy_dww = (const float*)d_in[14];
    const float* czy_dwb = (const float*)d_in[15];
    const float* czy_pww = (const float*)d_in[16];
    const float* czy_pwb = (const float*)d_in[17];
    const float* dw_pww  = (const float*)d_in[18];
    const float* dw_pwb  = (const float*)d_in[19];
    const float* dw_dww  = (const float*)d_in[20];
    const float* dw_dwb  = (const float*)d_in[21];
    const float* n2w     = (const float*)d_in[22];
    const float* n2b     = (const float*)d_in[23];
    const float* ldw_dww = (const float*)d_in[24];
    const float* ldw_dwb = (const float*)d_in[25];
    const float* ldw_pww = (const float*)d_in[26];
    const float* ldw_pwb = (const float*)d_in[27];
    float* out = (float*)d_out;
    char* ws   = (char*)d_ws;

    // layout (bytes): att_xy bf16 4MiB | att_zx/zy f32 64KB | pwb16 32KB |
    //                 dwwT 4KB | g 16MiB | z 64MiB | stats 2MiB
    ushort_t* att_xy = (ushort_t*)ws;
    float* att_zx = (float*)(ws + 4194304);
    float* att_zy = att_zx + 32 * 256;
    ushort_t* pwb16 = (ushort_t*)(att_zy + 32 * 256);
    ushort_t* dwwT  = pwb16 + 128 * 128;
    ushort_t* gbuf  = dwwT + 2048;
    ushort_t* zbuf  = gbuf + (size_t)4 * 65536 * 32;
    float2* stats   = (float2*)(zbuf + (size_t)4 * 65536 * 128);

    attxy_kernel<<<256, 256, 0, stream>>>(pxy, cxy_dww, cxy_dwb, cxy_pww, cxy_pwb, att_xy);
    attz_kernel<<<2, 256, 0, stream>>>(pzx, czx_dww, czx_dwb, czx_pww, czx_pwb,
                                       pzy, czy_dww, czy_dwb, czy_pww, czy_pwb,
                                       att_zx, att_zy);
    convert_pw_kernel<<<64, 256, 0, stream>>>(ldw_pww, pwb16);
    convert_ldwdw_kernel<<<5, 256, 0, stream>>>(ldw_dww, dwwT);
    ln1g_kernel<<<512, 256, 0, stream>>>(x, n1w, n1b, dw_pww, dw_pwb, gbuf, stats);
    fuse_kernel<<<4096, 256, 0, stream>>>(x, stats, n1w, n1b, n2w, n2b,
                                          att_xy, att_zx, att_zy,
                                          gbuf, dw_dww, dw_dwb, zbuf);
    ldw_kernel<<<4096, 256, 0, stream>>>(zbuf, dwwT, ldw_dwb, pwb16, ldw_pwb, out);
}

// Round 14
// 269.375 us; speedup vs baseline: 1.4221x; 1.0437x over previous
//
#include <hip/hip_runtime.h>
#include <hip/hip_bf16.h>
#include <math.h>

#define HH 256
#define WW 256
#define NB 4
#define NC 128
#define C4 32

typedef __attribute__((ext_vector_type(8))) short short8v;
typedef __attribute__((ext_vector_type(4))) float float4v;
typedef unsigned short ushort_t;

__device__ __forceinline__ float gelu_f(float v) {
    return 0.5f * v * (1.0f + erff(v * 0.7071067811865476f));
}
__device__ __forceinline__ unsigned short f2bf(float x) {
    __hip_bfloat16 h = __float2bfloat16(x);
    return __builtin_bit_cast(unsigned short, h);
}
__device__ __forceinline__ float bf2f(unsigned short u) {
    return __uint_as_float(((unsigned)u) << 16);
}
__device__ __forceinline__ float bfe(short8v v, int j) {
    return bf2f((ushort_t)v[j]);
}

// ------------------------------------------- att_xy (NHWC bf16 out) ----
__global__ void attxy_kernel(const float* __restrict__ params,
                             const float* __restrict__ dww, const float* __restrict__ dwb,
                             const float* __restrict__ pww, const float* __restrict__ pwb,
                             ushort_t* __restrict__ att)   // att[pix][32] bf16
{
    __shared__ float P[2048];
    __shared__ float DW[288];
    __shared__ float PW[1024];
    for (int i = threadIdx.x; i < 2048; i += 256) P[i] = params[i];
    for (int i = threadIdx.x; i < 288;  i += 256) DW[i] = dww[i];
    for (int i = threadIdx.x; i < 1024; i += 256) PW[i] = pww[i];
    __syncthreads();
    const int idx = blockIdx.x * 256 + threadIdx.x;
    const int h = idx >> 8, w = idx & 255;

    int iy0[3], iy1[3], ix0[3], ix1[3];
    float fy[3], fx[3];
    bool vy[3], vx[3];
#pragma unroll
    for (int d = 0; d < 3; ++d) {
        int hh = h - 1 + d;
        vy[d] = (hh >= 0 && hh < HH);
        float cy = hh * (7.0f / 255.0f);
        int i0 = (int)floorf(cy); i0 = min(max(i0, 0), 7);
        iy0[d] = i0; iy1[d] = min(i0 + 1, 7); fy[d] = cy - (float)i0;
        int ww2 = w - 1 + d;
        vx[d] = (ww2 >= 0 && ww2 < WW);
        float cx = ww2 * (7.0f / 255.0f);
        int j0 = (int)floorf(cx); j0 = min(max(j0, 0), 7);
        ix0[d] = j0; ix1[d] = min(j0 + 1, 7); fx[d] = cx - (float)j0;
    }
    float g[32];
#pragma unroll
    for (int c = 0; c < 32; ++c) {
        float a = dwb[c];
        const float* Pc = P + c * 64;
#pragma unroll
        for (int dy = 0; dy < 3; ++dy) {
            if (!vy[dy]) continue;
#pragma unroll
            for (int dx = 0; dx < 3; ++dx) {
                if (!vx[dx]) continue;
                float p00 = Pc[iy0[dy] * 8 + ix0[dx]];
                float p01 = Pc[iy0[dy] * 8 + ix1[dx]];
                float p10 = Pc[iy1[dy] * 8 + ix0[dx]];
                float p11 = Pc[iy1[dy] * 8 + ix1[dx]];
                float pt = p00 + (p01 - p00) * fx[dx];
                float pb = p10 + (p11 - p10) * fx[dx];
                float p  = pt + (pb - pt) * fy[dy];
                a += DW[c * 9 + dy * 3 + dx] * p;
            }
        }
        g[c] = gelu_f(a);
    }
    ushort_t* ap = att + (size_t)idx * 32;
#pragma unroll
    for (int q = 0; q < 4; ++q) {
        short8v pk;
#pragma unroll
        for (int j = 0; j < 8; ++j) {
            const int co = q * 8 + j;
            float a = pwb[co];
#pragma unroll
            for (int c = 0; c < 32; ++c) a += PW[co * 32 + c] * g[c];
            pk[j] = (short)f2bf(a);
        }
        *(short8v*)(ap + q * 8) = pk;
    }
}

// ------------------------------------------------------------ att_zx/zy ----
__global__ void attz_kernel(const float* __restrict__ params_zx, const float* __restrict__ zx_dww,
                            const float* __restrict__ zx_dwb, const float* __restrict__ zx_pww,
                            const float* __restrict__ zx_pwb,
                            const float* __restrict__ params_zy, const float* __restrict__ zy_dww,
                            const float* __restrict__ zy_dwb, const float* __restrict__ zy_pww,
                            const float* __restrict__ zy_pwb,
                            float* __restrict__ att_zx, float* __restrict__ att_zy)
{
    const bool sel = (blockIdx.x != 0);
    const float* params = sel ? params_zy : params_zx;
    const float* dww = sel ? zy_dww : zx_dww;
    const float* dwb = sel ? zy_dwb : zx_dwb;
    const float* pww = sel ? zy_pww : zx_pww;
    const float* pwb = sel ? zy_pwb : zx_pwb;
    float* att = sel ? att_zy : att_zx;
    const int pos = threadIdx.x;
    float g[32];
#pragma unroll
    for (int c = 0; c < 32; ++c) {
        float a = dwb[c];
#pragma unroll
        for (int d = 0; d < 3; ++d) {
            int p = pos - 1 + d;
            if (p < 0 || p > 255) continue;
            float cz = p * (7.0f / 255.0f);
            int i0 = (int)floorf(cz); i0 = min(max(i0, 0), 7);
            int i1 = min(i0 + 1, 7);
            float f = cz - (float)i0;
            float pv = params[c * 8 + i0];
            pv += (params[c * 8 + i1] - pv) * f;
            a += dww[c * 3 + d] * pv;
        }
        g[c] = gelu_f(a);
    }
#pragma unroll
    for (int co = 0; co < 32; ++co) {
        float a = pwb[co];
#pragma unroll
        for (int ci = 0; ci < 32; ++ci) a += pww[co * 32 + ci] * g[ci];
        att[co * 256 + pos] = a;
    }
}

// -------------------------------------------- pw fp32 -> bf16 [co][ci] ----
__global__ void convert_pw_kernel(const float* __restrict__ pw, ushort_t* __restrict__ pwb16) {
    int i = blockIdx.x * 256 + threadIdx.x;
    pwb16[i] = f2bf(pw[i]);
}

// ---------------------------------- ldw dw weights -> bf16 [tap][128] ----
__global__ void convert_ldwdw_kernel(const float* __restrict__ dww, ushort_t* __restrict__ dwwT) {
    int i = blockIdx.x * 256 + threadIdx.x;
    if (i < 1152) {
        int c = i / 9, tap = i % 9;
        dwwT[tap * 128 + c] = f2bf(dww[i]);
    }
}

// ------------------------------------------------------------- K1: ln1g ----
// thread = 1 px, grid = 1024 (4 blocks/CU -> 4 waves/SIMD; R13's 512-block
// 2px/thread version was grid-limited at 2 waves/SIMD, Occ 21%).
__global__ __launch_bounds__(256, 3) void ln1g_kernel(
    const float* __restrict__ x,
    const float* __restrict__ n1w, const float* __restrict__ n1b,
    const float* __restrict__ pww, const float* __restrict__ pwb,
    ushort_t* __restrict__ g, float2* __restrict__ stats)
{
    const int b = blockIdx.x >> 8, h = blockIdx.x & 255, w = threadIdx.x;
    const int pix = h * WW + w;
    const float* xp = x + (size_t)b * NC * 65536 + pix;

    float s1 = 0.f, s2 = 0.f;
    float x4v[32];
#pragma unroll
    for (int k = 0; k < 96; ++k) {
        float v = xp[(size_t)k * 65536];
        s1 += v; s2 += v * v;
    }
#pragma unroll
    for (int j = 0; j < 32; ++j) {
        float v = xp[(size_t)(96 + j) * 65536];
        x4v[j] = v; s1 += v; s2 += v * v;
    }
    const float m = s1 * (1.f / 128.f);
    const float r = rsqrtf(s2 * (1.f / 128.f) - m * m + 1e-6f);
    stats[(size_t)b * 65536 + pix] = float2{m, r};

#pragma unroll
    for (int j = 0; j < 32; ++j)
        x4v[j] = (x4v[j] - m) * r * n1w[96 + j] + n1b[96 + j];

    ushort_t* gp = g + ((size_t)b * 65536 + pix) * 32;
#pragma unroll
    for (int q = 0; q < 4; ++q) {
        short8v pk;
#pragma unroll
        for (int j = 0; j < 8; ++j) {
            const int co = q * 8 + j;
            float a = pwb[co];
#pragma unroll
            for (int jj = 0; jj < 32; ++jj) a += pww[co * 32 + jj] * x4v[jj];
            pk[j] = (short)f2bf(gelu_f(a));
        }
        *(short8v*)(gp + q * 8) = pk;
    }
}

// ------------------------------------------------------------- K2: fuse ----
// Block = 64-px strip; 256 thr = 4 q-groups x 64 px. g staged in LDS.
// R13-measured configuration — unchanged.
__global__ __launch_bounds__(256) void fuse_kernel(
    const float* __restrict__ x, const float2* __restrict__ stats,
    const float* __restrict__ n1w, const float* __restrict__ n1b,
    const float* __restrict__ n2w, const float* __restrict__ n2b,
    const ushort_t* __restrict__ att_xy, const float* __restrict__ att_zx,
    const float* __restrict__ att_zy,
    const ushort_t* __restrict__ g,
    const float* __restrict__ dww, const float* __restrict__ dwb,
    ushort_t* __restrict__ z)
{
    __shared__ __align__(16) ushort_t gs[3][66][40];
    __shared__ float rs[4][64];
    __shared__ float rq[4][64];

    const int lid  = (blockIdx.x & 7) * 512 + (blockIdx.x >> 3);
    const int b     = lid >> 10;
    const int h     = (lid >> 2) & 255;
    const int strip = lid & 3;
    const int tid = threadIdx.x;
    const int q  = tid >> 6;
    const int px = tid & 63;
    const int w  = strip * 64 + px;
    const int pix = h * WW + w;
    const int w0g = strip * 64;

    for (int i = tid; i < 792; i += 256) {
        const int row  = i / 264;
        const int rem  = i % 264;
        const int colc = rem >> 2;
        const int q8   = rem & 3;
        const int hy = min(max(h - 1 + row, 0), 255);
        const int cg = min(max(w0g + colc - 1, 0), 255);
        const short8v v = *(const short8v*)(g + ((size_t)b * 65536 + hy * WW + cg) * 32 + q8 * 8);
        *(short8v*)&gs[row][colc][q8 * 8] = v;
    }
    __syncthreads();

    const float2 st = stats[(size_t)b * 65536 + pix];
    const float m1 = st.x, r1 = st.y;

    float xn[4][8], u[4][8];
    {
        const short8v av = *(const short8v*)(att_xy + (size_t)pix * 32 + q * 8);
#pragma unroll
        for (int j = 0; j < 8; ++j) {
            const int c = q * 8 + j;
            float xv = x[((size_t)(b * NC + c)) * 65536 + pix];
            float v = (xv - m1) * r1 * n1w[c] + n1b[c];
            xn[0][j] = v; u[0][j] = v * bfe(av, j);
        }
    }
#pragma unroll
    for (int j = 0; j < 8; ++j) {
        const int c = 32 + q * 8 + j;
        float xv = x[((size_t)(b * NC + c)) * 65536 + pix];
        float v = (xv - m1) * r1 * n1w[c] + n1b[c];
        xn[1][j] = v; u[1][j] = v * att_zx[(c - 32) * 256 + h];
    }
#pragma unroll
    for (int j = 0; j < 8; ++j) {
        const int c = 64 + q * 8 + j;
        float xv = x[((size_t)(b * NC + c)) * 65536 + pix];
        float v = (xv - m1) * r1 * n1w[c] + n1b[c];
        xn[2][j] = v; u[2][j] = v * att_zy[(c - 64) * 256 + w];
    }
    {
        float a[8];
#pragma unroll
        for (int j = 0; j < 8; ++j) a[j] = dwb[q * 8 + j];
        const float ml = (w > 0) ? 1.f : 0.f;
        const float mr = (w < 255) ? 1.f : 0.f;
#pragma unroll
        for (int dy = -1; dy <= 1; ++dy) {
            int hy = h + dy;
            if (hy < 0 || hy > 255) continue;
            const int rr = dy + 1;
            short8v gl = *(const short8v*)&gs[rr][px][q * 8];
            short8v gc = *(const short8v*)&gs[rr][px + 1][q * 8];
            short8v gv = *(const short8v*)&gs[rr][px + 2][q * 8];
            const int r0 = rr * 3;
#pragma unroll
            for (int j = 0; j < 8; ++j) {
                const float* wk = dww + (q * 8 + j) * 9 + r0;
                a[j] += (wk[0] * ml) * bfe(gl, j);
                a[j] += wk[1] * bfe(gc, j);
                a[j] += (wk[2] * mr) * bfe(gv, j);
            }
        }
#pragma unroll
        for (int j = 0; j < 8; ++j) {
            const int c = 96 + q * 8 + j;
            float xv = x[((size_t)(b * NC + c)) * 65536 + pix];
            xn[3][j] = (xv - m1) * r1 * n1w[c] + n1b[c];
            u[3][j] = a[j];
        }
    }
    float e1 = 0.f, e2 = 0.f;
#pragma unroll
    for (int br = 0; br < 4; ++br)
#pragma unroll
        for (int j = 0; j < 8; ++j) { e1 += u[br][j]; e2 += u[br][j] * u[br][j]; }
    rs[q][px] = e1; rq[q][px] = e2;
    __syncthreads();
    const float ssum = rs[0][px] + rs[1][px] + rs[2][px] + rs[3][px];
    const float qsum = rq[0][px] + rq[1][px] + rq[2][px] + rq[3][px];
    const float m2 = ssum * (1.f / 128.f);
    const float r2 = rsqrtf(qsum * (1.f / 128.f) - m2 * m2 + 1e-6f);
    ushort_t* zp = z + ((size_t)b * 65536 + pix) * 128;
#pragma unroll
    for (int br = 0; br < 4; ++br) {
        short8v pk;
#pragma unroll
        for (int j = 0; j < 8; ++j) {
            const int c = br * 32 + q * 8 + j;
            pk[j] = (short)f2bf((u[br][j] - m2) * r2 * n2w[c] + n2b[c] + xn[br][j]);
        }
        *(short8v*)(zp + br * 32 + q * 8) = pk;
    }
}

// --------------------------------------------------------------- ldw ----
// R7-exact (LOCKED, 95 us measured R11/R13): launch_bounds (256,3). (256,5)
// forces VGPR 84->48, rematerializes z loads (FETCH 54->293MB, 115->223us,
// R10). Px mapping it*16+pr is wave-contiguous; R8/R9 remaps inflated
// traffic 3-5x. Do not modify without counter evidence.
__global__ __launch_bounds__(256, 3) void ldw_kernel(
    const ushort_t* __restrict__ z, const ushort_t* __restrict__ dwwT,
    const float* __restrict__ dwb, const ushort_t* __restrict__ wb16,
    const float* __restrict__ pwb, float* __restrict__ out)
{
    __shared__ __align__(16) ushort_t tl[64 * 128];

    const int lid  = (blockIdx.x & 7) * 512 + (blockIdx.x >> 3);
    const int b    = lid >> 10;
    const int h    = (lid >> 2) & 255;
    const int px0  = (lid & 3) * 64;
    const int tid  = threadIdx.x;

    {
        const int oc = tid & 15;
        const int pr = tid >> 4;
        short8v wt[9];
#pragma unroll
        for (int t = 0; t < 9; ++t)
            wt[t] = *(const short8v*)(dwwT + t * 128 + oc * 8);
        const float4 bd0 = *(const float4*)(dwb + oc * 8);
        const float4 bd1 = *(const float4*)(dwb + oc * 8 + 4);
        const float bdw[8] = {bd0.x, bd0.y, bd0.z, bd0.w, bd1.x, bd1.y, bd1.z, bd1.w};
        char* tlb = (char*)tl;
#pragma unroll
        for (int it = 0; it < 4; ++it) {
            const int px = it * 16 + pr;
            const int w  = px0 + px;
            const int wl = (w > 0) ? w - 1 : 0;
            const int wr2 = (w < 255) ? w + 1 : 255;
            const float ml = (w > 0) ? 1.f : 0.f;
            const float mr = (w < 255) ? 1.f : 0.f;
            float a[8];
#pragma unroll
            for (int j = 0; j < 8; ++j) a[j] = bdw[j];
#pragma unroll
            for (int dy = -1; dy <= 1; ++dy) {
                int hy = h + dy;
                if (hy < 0 || hy > 255) continue;
                const ushort_t* zr = z + ((size_t)b * 65536 + hy * WW) * 128 + oc * 8;
                short8v vl = *(const short8v*)(zr + (size_t)wl * 128);
                short8v vc = *(const short8v*)(zr + (size_t)w * 128);
                short8v vr = *(const short8v*)(zr + (size_t)wr2 * 128);
                const int r0 = (dy + 1) * 3;
#pragma unroll
                for (int j = 0; j < 8; ++j) {
                    a[j] += (bfe(wt[r0], j) * ml) * bfe(vl, j);
                    a[j] += bfe(wt[r0 + 1], j) * bfe(vc, j);
                    a[j] += (bfe(wt[r0 + 2], j) * mr) * bfe(vr, j);
                }
            }
            short8v pk;
#pragma unroll
            for (int j = 0; j < 8; ++j) pk[j] = (short)f2bf(gelu_f(a[j]));
            const int chunk = oc ^ (px & 15);
            *(short8v*)(tlb + px * 256 + chunk * 16) = pk;
        }
    }
    __syncthreads();

    const int lane = tid & 63;
    const int wv   = tid >> 6;
    const int l15  = lane & 15;
    const int l4   = lane >> 4;

    short8v afrag[2][4];
#pragma unroll
    for (int ct = 0; ct < 2; ++ct) {
        const int co = wv * 32 + ct * 16 + l15;
#pragma unroll
        for (int ks = 0; ks < 4; ++ks)
            afrag[ct][ks] = *(const short8v*)(wb16 + co * 128 + ks * 32 + l4 * 8);
    }
    float4v bias[2];
#pragma unroll
    for (int ct = 0; ct < 2; ++ct) {
        const float4 bv = *(const float4*)(pwb + wv * 32 + ct * 16 + l4 * 4);
        bias[ct] = float4v{bv.x, bv.y, bv.z, bv.w};
    }

    const char* tlb = (const char*)tl;
#pragma unroll
    for (int pt = 0; pt < 4; ++pt) {
        const int px = pt * 16 + l15;
        short8v bfrag[4];
#pragma unroll
        for (int ks = 0; ks < 4; ++ks) {
            const int chunk = (ks * 4 + l4) ^ (px & 15);
            bfrag[ks] = *(const short8v*)(tlb + px * 256 + chunk * 16);
        }
        float4v acc0 = bias[0];
        float4v acc1 = bias[1];
#pragma unroll
        for (int ks = 0; ks < 4; ++ks) {
            acc0 = __builtin_amdgcn_mfma_f32_16x16x32_bf16(afrag[0][ks], bfrag[ks], acc0, 0, 0, 0);
            acc1 = __builtin_amdgcn_mfma_f32_16x16x32_bf16(afrag[1][ks], bfrag[ks], acc1, 0, 0, 0);
        }
#pragma unroll
        for (int ct = 0; ct < 2; ++ct) {
            const int co = wv * 32 + ct * 16 + l4 * 4;
            float* op = out + ((size_t)(b * NC + co)) * 65536 + h * WW + px0 + pt * 16 + l15;
            const float4v av = ct ? acc1 : acc0;
#pragma unroll
            for (int r = 0; r < 4; ++r) op[(size_t)r * 65536] = av[r];
        }
    }
}

// ------------------------------------------------------------- launch ----
extern "C" void kernel_launch(void* const* d_in, const int* in_sizes, int n_in,
                              void* d_out, int out_size, void* d_ws, size_t ws_size,
                              hipStream_t stream)
{
    (void)in_sizes; (void)n_in; (void)out_size; (void)ws_size;
    const float* x       = (const float*)d_in[0];
    const float* n1w     = (const float*)d_in[1];
    const float* n1b     = (const float*)d_in[2];
    const float* pxy     = (const float*)d_in[3];
    const float* cxy_dww = (const float*)d_in[4];
    const float* cxy_dwb = (const float*)d_in[5];
    const float* cxy_pww = (const float*)d_in[6];
    const float* cxy_pwb = (const float*)d_in[7];
    const float* pzx     = (const float*)d_in[8];
    const float* czx_dww = (const float*)d_in[9];
    const float* czx_dwb = (const float*)d_in[10];
    const float* czx_pww = (const float*)d_in[11];
    const float* czx_pwb = (const float*)d_in[12];
    const float* pzy     = (const float*)d_in[13];
    const float* czy_dww = (const float*)d_in[14];
    const float* czy_dwb = (const float*)d_in[15];
    const float* czy_pww = (const float*)d_in[16];
    const float* czy_pwb = (const float*)d_in[17];
    const float* dw_pww  = (const float*)d_in[18];
    const float* dw_pwb  = (const float*)d_in[19];
    const float* dw_dww  = (const float*)d_in[20];
    const float* dw_dwb  = (const float*)d_in[21];
    const float* n2w     = (const float*)d_in[22];
    const float* n2b     = (const float*)d_in[23];
    const float* ldw_dww = (const float*)d_in[24];
    const float* ldw_dwb = (const float*)d_in[25];
    const float* ldw_pww = (const float*)d_in[26];
    const float* ldw_pwb = (const float*)d_in[27];
    float* out = (float*)d_out;
    char* ws   = (char*)d_ws;

    // layout (bytes): att_xy bf16 4MiB | att_zx/zy f32 64KB | pwb16 32KB |
    //                 dwwT 4KB | g 16MiB | z 64MiB | stats 2MiB
    ushort_t* att_xy = (ushort_t*)ws;
    float* att_zx = (float*)(ws + 4194304);
    float* att_zy = att_zx + 32 * 256;
    ushort_t* pwb16 = (ushort_t*)(att_zy + 32 * 256);
    ushort_t* dwwT  = pwb16 + 128 * 128;
    ushort_t* gbuf  = dwwT + 2048;
    ushort_t* zbuf  = gbuf + (size_t)4 * 65536 * 32;
    float2* stats   = (float2*)(zbuf + (size_t)4 * 65536 * 128);

    attxy_kernel<<<256, 256, 0, stream>>>(pxy, cxy_dww, cxy_dwb, cxy_pww, cxy_pwb, att_xy);
    attz_kernel<<<2, 256, 0, stream>>>(pzx, czx_dww, czx_dwb, czx_pww, czx_pwb,
                                       pzy, czy_dww, czy_dwb, czy_pww, czy_pwb,
                                       att_zx, att_zy);
    convert_pw_kernel<<<64, 256, 0, stream>>>(ldw_pww, pwb16);
    convert_ldwdw_kernel<<<5, 256, 0, stream>>>(ldw_dww, dwwT);
    ln1g_kernel<<<1024, 256, 0, stream>>>(x, n1w, n1b, dw_pww, dw_pwb, gbuf, stats);
    fuse_kernel<<<4096, 256, 0, stream>>>(x, stats, n1w, n1b, n2w, n2b,
                                          att_xy, att_zx, att_zy,
                                          gbuf, dw_dww, dw_dwb, zbuf);
    ldw_kernel<<<4096, 256, 0, stream>>>(zbuf, dwwT, ldw_dwb, pwb16, ldw_pwb, out);
}

// Round 15
// 231.421 us; speedup vs baseline: 1.6553x; 1.1640x over previous
//
#include <hip/hip_runtime.h>
#include <hip/hip_bf16.h>
#include <math.h>

#define HH 256
#define WW 256
#define NB 4
#define NC 128
#define C4 32

typedef __attribute__((ext_vector_type(8))) short short8v;
typedef __attribute__((ext_vector_type(4))) float float4v;
typedef unsigned short ushort_t;

__device__ __forceinline__ float gelu_f(float v) {
    return 0.5f * v * (1.0f + erff(v * 0.7071067811865476f));
}
__device__ __forceinline__ unsigned short f2bf(float x) {
    __hip_bfloat16 h = __float2bfloat16(x);
    return __builtin_bit_cast(unsigned short, h);
}
__device__ __forceinline__ float bf2f(unsigned short u) {
    return __uint_as_float(((unsigned)u) << 16);
}
__device__ __forceinline__ float bfe(short8v v, int j) {
    return bf2f((ushort_t)v[j]);
}

// ------------------------------------------------------------- prep ----
// One kernel, 327 blocks: [0,256) attxy | [256,258) attz | [258,322)
// convert_pw | [322,327) convert_ldwdw. Saves 3 serialized launch gaps.
__global__ __launch_bounds__(256) void prep_kernel(
    const float* __restrict__ pxy,
    const float* __restrict__ cxy_dww, const float* __restrict__ cxy_dwb,
    const float* __restrict__ cxy_pww, const float* __restrict__ cxy_pwb,
    const float* __restrict__ pzx, const float* __restrict__ zx_dww,
    const float* __restrict__ zx_dwb, const float* __restrict__ zx_pww,
    const float* __restrict__ zx_pwb,
    const float* __restrict__ pzy, const float* __restrict__ zy_dww,
    const float* __restrict__ zy_dwb, const float* __restrict__ zy_pww,
    const float* __restrict__ zy_pwb,
    const float* __restrict__ ldw_pww, const float* __restrict__ ldw_dww,
    ushort_t* __restrict__ att_xy, float* __restrict__ att_zx,
    float* __restrict__ att_zy, ushort_t* __restrict__ pwb16,
    ushort_t* __restrict__ dwwT)
{
    const int bid = blockIdx.x;
    if (bid >= 258) {
        if (bid < 322) {            // convert_pw: 64 blocks x 256
            int i = (bid - 258) * 256 + threadIdx.x;
            pwb16[i] = f2bf(ldw_pww[i]);
        } else {                    // convert_ldwdw: 5 blocks x 256
            int i = (bid - 322) * 256 + threadIdx.x;
            if (i < 1152) {
                int c = i / 9, tap = i % 9;
                dwwT[tap * 128 + c] = f2bf(ldw_dww[i]);
            }
        }
        return;
    }
    if (bid >= 256) {               // attz: 2 blocks
        const bool sel = (bid != 256);
        const float* params = sel ? pzy : pzx;
        const float* dww = sel ? zy_dww : zx_dww;
        const float* dwb = sel ? zy_dwb : zx_dwb;
        const float* pww = sel ? zy_pww : zx_pww;
        const float* pwb = sel ? zy_pwb : zx_pwb;
        float* att = sel ? att_zy : att_zx;
        const int pos = threadIdx.x;
        float g[32];
#pragma unroll
        for (int c = 0; c < 32; ++c) {
            float a = dwb[c];
#pragma unroll
            for (int d = 0; d < 3; ++d) {
                int p = pos - 1 + d;
                if (p < 0 || p > 255) continue;
                float cz = p * (7.0f / 255.0f);
                int i0 = (int)floorf(cz); i0 = min(max(i0, 0), 7);
                int i1 = min(i0 + 1, 7);
                float f = cz - (float)i0;
                float pv = params[c * 8 + i0];
                pv += (params[c * 8 + i1] - pv) * f;
                a += dww[c * 3 + d] * pv;
            }
            g[c] = gelu_f(a);
        }
#pragma unroll
        for (int co = 0; co < 32; ++co) {
            float a = pwb[co];
#pragma unroll
            for (int ci = 0; ci < 32; ++ci) a += pww[co * 32 + ci] * g[ci];
            att[co * 256 + pos] = a;
        }
        return;
    }
    // ---- attxy: 256 blocks ----
    __shared__ float P[2048];
    __shared__ float DW[288];
    __shared__ float PW[1024];
    for (int i = threadIdx.x; i < 2048; i += 256) P[i] = pxy[i];
    for (int i = threadIdx.x; i < 288;  i += 256) DW[i] = cxy_dww[i];
    for (int i = threadIdx.x; i < 1024; i += 256) PW[i] = cxy_pww[i];
    __syncthreads();
    const int idx = bid * 256 + threadIdx.x;
    const int h = idx >> 8, w = idx & 255;

    int iy0[3], iy1[3], ix0[3], ix1[3];
    float fy[3], fx[3];
    bool vy[3], vx[3];
#pragma unroll
    for (int d = 0; d < 3; ++d) {
        int hh = h - 1 + d;
        vy[d] = (hh >= 0 && hh < HH);
        float cy = hh * (7.0f / 255.0f);
        int i0 = (int)floorf(cy); i0 = min(max(i0, 0), 7);
        iy0[d] = i0; iy1[d] = min(i0 + 1, 7); fy[d] = cy - (float)i0;
        int ww2 = w - 1 + d;
        vx[d] = (ww2 >= 0 && ww2 < WW);
        float cx = ww2 * (7.0f / 255.0f);
        int j0 = (int)floorf(cx); j0 = min(max(j0, 0), 7);
        ix0[d] = j0; ix1[d] = min(j0 + 1, 7); fx[d] = cx - (float)j0;
    }
    float g[32];
#pragma unroll
    for (int c = 0; c < 32; ++c) {
        float a = cxy_dwb[c];
        const float* Pc = P + c * 64;
#pragma unroll
        for (int dy = 0; dy < 3; ++dy) {
            if (!vy[dy]) continue;
#pragma unroll
            for (int dx = 0; dx < 3; ++dx) {
                if (!vx[dx]) continue;
                float p00 = Pc[iy0[dy] * 8 + ix0[dx]];
                float p01 = Pc[iy0[dy] * 8 + ix1[dx]];
                float p10 = Pc[iy1[dy] * 8 + ix0[dx]];
                float p11 = Pc[iy1[dy] * 8 + ix1[dx]];
                float pt = p00 + (p01 - p00) * fx[dx];
                float pb = p10 + (p11 - p10) * fx[dx];
                float p  = pt + (pb - pt) * fy[dy];
                a += DW[c * 9 + dy * 3 + dx] * p;
            }
        }
        g[c] = gelu_f(a);
    }
    ushort_t* ap = att_xy + (size_t)idx * 32;
#pragma unroll
    for (int q = 0; q < 4; ++q) {
        short8v pk;
#pragma unroll
        for (int j = 0; j < 8; ++j) {
            const int co = q * 8 + j;
            float a = cxy_pwb[co];
#pragma unroll
            for (int c = 0; c < 32; ++c) a += PW[co * 32 + c] * g[c];
            pk[j] = (short)f2bf(a);
        }
        *(short8v*)(ap + q * 8) = pk;
    }
}

// ------------------------------------------------------------- K1: ln1g ----
// thread = 1 px, grid = 1024 (R14-measured, locked).
__global__ __launch_bounds__(256, 3) void ln1g_kernel(
    const float* __restrict__ x,
    const float* __restrict__ n1w, const float* __restrict__ n1b,
    const float* __restrict__ pww, const float* __restrict__ pwb,
    ushort_t* __restrict__ g, float2* __restrict__ stats)
{
    const int b = blockIdx.x >> 8, h = blockIdx.x & 255, w = threadIdx.x;
    const int pix = h * WW + w;
    const float* xp = x + (size_t)b * NC * 65536 + pix;

    float s1 = 0.f, s2 = 0.f;
    float x4v[32];
#pragma unroll
    for (int k = 0; k < 96; ++k) {
        float v = xp[(size_t)k * 65536];
        s1 += v; s2 += v * v;
    }
#pragma unroll
    for (int j = 0; j < 32; ++j) {
        float v = xp[(size_t)(96 + j) * 65536];
        x4v[j] = v; s1 += v; s2 += v * v;
    }
    const float m = s1 * (1.f / 128.f);
    const float r = rsqrtf(s2 * (1.f / 128.f) - m * m + 1e-6f);
    stats[(size_t)b * 65536 + pix] = float2{m, r};

#pragma unroll
    for (int j = 0; j < 32; ++j)
        x4v[j] = (x4v[j] - m) * r * n1w[96 + j] + n1b[96 + j];

    ushort_t* gp = g + ((size_t)b * 65536 + pix) * 32;
#pragma unroll
    for (int q = 0; q < 4; ++q) {
        short8v pk;
#pragma unroll
        for (int j = 0; j < 8; ++j) {
            const int co = q * 8 + j;
            float a = pwb[co];
#pragma unroll
            for (int jj = 0; jj < 32; ++jj) a += pww[co * 32 + jj] * x4v[jj];
            pk[j] = (short)f2bf(gelu_f(a));
        }
        *(short8v*)(gp + q * 8) = pk;
    }
}

// ------------------------------------------------------------- K2: fuse ----
// R15 change (isolated): x/stats/att loads + normalize issued BEFORE the
// g-staging, so their HBM latency overlaps the staging loads + barrier.
// Live set across barrier = xn[4][8]+u[3][8] (same as before; no VGPR cost).
__global__ __launch_bounds__(256) void fuse_kernel(
    const float* __restrict__ x, const float2* __restrict__ stats,
    const float* __restrict__ n1w, const float* __restrict__ n1b,
    const float* __restrict__ n2w, const float* __restrict__ n2b,
    const ushort_t* __restrict__ att_xy, const float* __restrict__ att_zx,
    const float* __restrict__ att_zy,
    const ushort_t* __restrict__ g,
    const float* __restrict__ dww, const float* __restrict__ dwb,
    ushort_t* __restrict__ z)
{
    __shared__ __align__(16) ushort_t gs[3][66][40];
    __shared__ float rs[4][64];
    __shared__ float rq[4][64];

    const int lid  = (blockIdx.x & 7) * 512 + (blockIdx.x >> 3);
    const int b     = lid >> 10;
    const int h     = (lid >> 2) & 255;
    const int strip = lid & 3;
    const int tid = threadIdx.x;
    const int q  = tid >> 6;
    const int px = tid & 63;
    const int w  = strip * 64 + px;
    const int pix = h * WW + w;
    const int w0g = strip * 64;

    // ---- phase 1: x-branch loads + normalize (issued before staging) ----
    const float2 st = stats[(size_t)b * 65536 + pix];
    const float m1 = st.x, r1 = st.y;

    float xn[4][8], u[4][8];
    {
        const short8v av = *(const short8v*)(att_xy + (size_t)pix * 32 + q * 8);
#pragma unroll
        for (int j = 0; j < 8; ++j) {
            const int c = q * 8 + j;
            float xv = x[((size_t)(b * NC + c)) * 65536 + pix];
            float v = (xv - m1) * r1 * n1w[c] + n1b[c];
            xn[0][j] = v; u[0][j] = v * bfe(av, j);
        }
    }
#pragma unroll
    for (int j = 0; j < 8; ++j) {
        const int c = 32 + q * 8 + j;
        float xv = x[((size_t)(b * NC + c)) * 65536 + pix];
        float v = (xv - m1) * r1 * n1w[c] + n1b[c];
        xn[1][j] = v; u[1][j] = v * att_zx[(c - 32) * 256 + h];
    }
#pragma unroll
    for (int j = 0; j < 8; ++j) {
        const int c = 64 + q * 8 + j;
        float xv = x[((size_t)(b * NC + c)) * 65536 + pix];
        float v = (xv - m1) * r1 * n1w[c] + n1b[c];
        xn[2][j] = v; u[2][j] = v * att_zy[(c - 64) * 256 + w];
    }
#pragma unroll
    for (int j = 0; j < 8; ++j) {
        const int c = 96 + q * 8 + j;
        float xv = x[((size_t)(b * NC + c)) * 65536 + pix];
        xn[3][j] = (xv - m1) * r1 * n1w[c] + n1b[c];
    }

    // ---- phase 2: stage g[3][66][32] into LDS ----
    for (int i = tid; i < 792; i += 256) {
        const int row  = i / 264;
        const int rem  = i % 264;
        const int colc = rem >> 2;
        const int q8   = rem & 3;
        const int hy = min(max(h - 1 + row, 0), 255);
        const int cg = min(max(w0g + colc - 1, 0), 255);
        const short8v v = *(const short8v*)(g + ((size_t)b * 65536 + hy * WW + cg) * 32 + q8 * 8);
        *(short8v*)&gs[row][colc][q8 * 8] = v;
    }
    __syncthreads();

    // ---- phase 3: dw3x3 over staged g ----
    {
        float a[8];
#pragma unroll
        for (int j = 0; j < 8; ++j) a[j] = dwb[q * 8 + j];
        const float ml = (w > 0) ? 1.f : 0.f;
        const float mr = (w < 255) ? 1.f : 0.f;
#pragma unroll
        for (int dy = -1; dy <= 1; ++dy) {
            int hy = h + dy;
            if (hy < 0 || hy > 255) continue;   // block-uniform
            const int rr = dy + 1;
            short8v gl = *(const short8v*)&gs[rr][px][q * 8];
            short8v gc = *(const short8v*)&gs[rr][px + 1][q * 8];
            short8v gv = *(const short8v*)&gs[rr][px + 2][q * 8];
            const int r0 = rr * 3;
#pragma unroll
            for (int j = 0; j < 8; ++j) {
                const float* wk = dww + (q * 8 + j) * 9 + r0;
                a[j] += (wk[0] * ml) * bfe(gl, j);
                a[j] += wk[1] * bfe(gc, j);
                a[j] += (wk[2] * mr) * bfe(gv, j);
            }
        }
#pragma unroll
        for (int j = 0; j < 8; ++j) u[3][j] = a[j];
    }
    // ---- LN2 stats ----
    float e1 = 0.f, e2 = 0.f;
#pragma unroll
    for (int br = 0; br < 4; ++br)
#pragma unroll
        for (int j = 0; j < 8; ++j) { e1 += u[br][j]; e2 += u[br][j] * u[br][j]; }
    rs[q][px] = e1; rq[q][px] = e2;
    __syncthreads();
    const float ssum = rs[0][px] + rs[1][px] + rs[2][px] + rs[3][px];
    const float qsum = rq[0][px] + rq[1][px] + rq[2][px] + rq[3][px];
    const float m2 = ssum * (1.f / 128.f);
    const float r2 = rsqrtf(qsum * (1.f / 128.f) - m2 * m2 + 1e-6f);
    ushort_t* zp = z + ((size_t)b * 65536 + pix) * 128;
#pragma unroll
    for (int br = 0; br < 4; ++br) {
        short8v pk;
#pragma unroll
        for (int j = 0; j < 8; ++j) {
            const int c = br * 32 + q * 8 + j;
            pk[j] = (short)f2bf((u[br][j] - m2) * r2 * n2w[c] + n2b[c] + xn[br][j]);
        }
        *(short8v*)(zp + br * 32 + q * 8) = pk;
    }
}

// --------------------------------------------------------------- ldw ----
// R7-exact (LOCKED, ~95 us measured R11/R13/R14): launch_bounds (256,3).
// (256,5) forces VGPR 84->48, rematerializes z loads (FETCH 54->293MB,
// 115->223us, R10). Px mapping it*16+pr is wave-contiguous; R8/R9 remaps
// inflated traffic 3-5x. Do not modify without counter evidence.
__global__ __launch_bounds__(256, 3) void ldw_kernel(
    const ushort_t* __restrict__ z, const ushort_t* __restrict__ dwwT,
    const float* __restrict__ dwb, const ushort_t* __restrict__ wb16,
    const float* __restrict__ pwb, float* __restrict__ out)
{
    __shared__ __align__(16) ushort_t tl[64 * 128];

    const int lid  = (blockIdx.x & 7) * 512 + (blockIdx.x >> 3);
    const int b    = lid >> 10;
    const int h    = (lid >> 2) & 255;
    const int px0  = (lid & 3) * 64;
    const int tid  = threadIdx.x;

    {
        const int oc = tid & 15;
        const int pr = tid >> 4;
        short8v wt[9];
#pragma unroll
        for (int t = 0; t < 9; ++t)
            wt[t] = *(const short8v*)(dwwT + t * 128 + oc * 8);
        const float4 bd0 = *(const float4*)(dwb + oc * 8);
        const float4 bd1 = *(const float4*)(dwb + oc * 8 + 4);
        const float bdw[8] = {bd0.x, bd0.y, bd0.z, bd0.w, bd1.x, bd1.y, bd1.z, bd1.w};
        char* tlb = (char*)tl;
#pragma unroll
        for (int it = 0; it < 4; ++it) {
            const int px = it * 16 + pr;
            const int w  = px0 + px;
            const int wl = (w > 0) ? w - 1 : 0;
            const int wr2 = (w < 255) ? w + 1 : 255;
            const float ml = (w > 0) ? 1.f : 0.f;
            const float mr = (w < 255) ? 1.f : 0.f;
            float a[8];
#pragma unroll
            for (int j = 0; j < 8; ++j) a[j] = bdw[j];
#pragma unroll
            for (int dy = -1; dy <= 1; ++dy) {
                int hy = h + dy;
                if (hy < 0 || hy > 255) continue;
                const ushort_t* zr = z + ((size_t)b * 65536 + hy * WW) * 128 + oc * 8;
                short8v vl = *(const short8v*)(zr + (size_t)wl * 128);
                short8v vc = *(const short8v*)(zr + (size_t)w * 128);
                short8v vr = *(const short8v*)(zr + (size_t)wr2 * 128);
                const int r0 = (dy + 1) * 3;
#pragma unroll
                for (int j = 0; j < 8; ++j) {
                    a[j] += (bfe(wt[r0], j) * ml) * bfe(vl, j);
                    a[j] += bfe(wt[r0 + 1], j) * bfe(vc, j);
                    a[j] += (bfe(wt[r0 + 2], j) * mr) * bfe(vr, j);
                }
            }
            short8v pk;
#pragma unroll
            for (int j = 0; j < 8; ++j) pk[j] = (short)f2bf(gelu_f(a[j]));
            const int chunk = oc ^ (px & 15);
            *(short8v*)(tlb + px * 256 + chunk * 16) = pk;
        }
    }
    __syncthreads();

    const int lane = tid & 63;
    const int wv   = tid >> 6;
    const int l15  = lane & 15;
    const int l4   = lane >> 4;

    short8v afrag[2][4];
#pragma unroll
    for (int ct = 0; ct < 2; ++ct) {
        const int co = wv * 32 + ct * 16 + l15;
#pragma unroll
        for (int ks = 0; ks < 4; ++ks)
            afrag[ct][ks] = *(const short8v*)(wb16 + co * 128 + ks * 32 + l4 * 8);
    }
    float4v bias[2];
#pragma unroll
    for (int ct = 0; ct < 2; ++ct) {
        const float4 bv = *(const float4*)(pwb + wv * 32 + ct * 16 + l4 * 4);
        bias[ct] = float4v{bv.x, bv.y, bv.z, bv.w};
    }

    const char* tlb = (const char*)tl;
#pragma unroll
    for (int pt = 0; pt < 4; ++pt) {
        const int px = pt * 16 + l15;
        short8v bfrag[4];
#pragma unroll
        for (int ks = 0; ks < 4; ++ks) {
            const int chunk = (ks * 4 + l4) ^ (px & 15);
            bfrag[ks] = *(const short8v*)(tlb + px * 256 + chunk * 16);
        }
        float4v acc0 = bias[0];
        float4v acc1 = bias[1];
#pragma unroll
        for (int ks = 0; ks < 4; ++ks) {
            acc0 = __builtin_amdgcn_mfma_f32_16x16x32_bf16(afrag[0][ks], bfrag[ks], acc0, 0, 0, 0);
            acc1 = __builtin_amdgcn_mfma_f32_16x16x32_bf16(afrag[1][ks], bfrag[ks], acc1, 0, 0, 0);
        }
#pragma unroll
        for (int ct = 0; ct < 2; ++ct) {
            const int co = wv * 32 + ct * 16 + l4 * 4;
            float* op = out + ((size_t)(b * NC + co)) * 65536 + h * WW + px0 + pt * 16 + l15;
            const float4v av = ct ? acc1 : acc0;
#pragma unroll
            for (int r = 0; r < 4; ++r) op[(size_t)r * 65536] = av[r];
        }
    }
}

// ------------------------------------------------------------- launch ----
extern "C" void kernel_launch(void* const* d_in, const int* in_sizes, int n_in,
                              void* d_out, int out_size, void* d_ws, size_t ws_size,
                              hipStream_t stream)
{
    (void)in_sizes; (void)n_in; (void)out_size; (void)ws_size;
    const float* x       = (const float*)d_in[0];
    const float* n1w     = (const float*)d_in[1];
    const float* n1b     = (const float*)d_in[2];
    const float* pxy     = (const float*)d_in[3];
    const float* cxy_dww = (const float*)d_in[4];
    const float* cxy_dwb = (const float*)d_in[5];
    const float* cxy_pww = (const float*)d_in[6];
    const float* cxy_pwb = (const float*)d_in[7];
    const float* pzx     = (const float*)d_in[8];
    const float* czx_dww = (const float*)d_in[9];
    const float* czx_dwb = (const float*)d_in[10];
    const float* czx_pww = (const float*)d_in[11];
    const float* czx_pwb = (const float*)d_in[12];
    const float* pzy     = (const float*)d_in[13];
    const float* czy_dww = (const float*)d_in[14];
    const float* czy_dwb = (const float*)d_in[15];
    const float* czy_pww = (const float*)d_in[16];
    const float* czy_pwb = (const float*)d_in[17];
    const float* dw_pww  = (const float*)d_in[18];
    const float* dw_pwb  = (const float*)d_in[19];
    const float* dw_dww  = (const float*)d_in[20];
    const float* dw_dwb  = (const float*)d_in[21];
    const float* n2w     = (const float*)d_in[22];
    const float* n2b     = (const float*)d_in[23];
    const float* ldw_dww = (const float*)d_in[24];
    const float* ldw_dwb = (const float*)d_in[25];
    const float* ldw_pww = (const float*)d_in[26];
    const float* ldw_pwb = (const float*)d_in[27];
    float* out = (float*)d_out;
    char* ws   = (char*)d_ws;

    // layout (bytes): att_xy bf16 4MiB | att_zx/zy f32 64KB | pwb16 32KB |
    //                 dwwT 4KB | g 16MiB | z 64MiB | stats 2MiB
    ushort_t* att_xy = (ushort_t*)ws;
    float* att_zx = (float*)(ws + 4194304);
    float* att_zy = att_zx + 32 * 256;
    ushort_t* pwb16 = (ushort_t*)(att_zy + 32 * 256);
    ushort_t* dwwT  = pwb16 + 128 * 128;
    ushort_t* gbuf  = dwwT + 2048;
    ushort_t* zbuf  = gbuf + (size_t)4 * 65536 * 32;
    float2* stats   = (float2*)(zbuf + (size_t)4 * 65536 * 128);

    prep_kernel<<<327, 256, 0, stream>>>(pxy, cxy_dww, cxy_dwb, cxy_pww, cxy_pwb,
                                         pzx, czx_dww, czx_dwb, czx_pww, czx_pwb,
                                         pzy, czy_dww, czy_dwb, czy_pww, czy_pwb,
                                         ldw_pww, ldw_dww,
                                         att_xy, att_zx, att_zy, pwb16, dwwT);
    ln1g_kernel<<<1024, 256, 0, stream>>>(x, n1w, n1b, dw_pww, dw_pwb, gbuf, stats);
    fuse_kernel<<<4096, 256, 0, stream>>>(x, stats, n1w, n1b, n2w, n2b,
                                          att_xy, att_zx, att_zy,
                                          gbuf, dw_dww, dw_dwb, zbuf);
    ldw_kernel<<<4096, 256, 0, stream>>>(zbuf, dwwT, ldw_dwb, pwb16, ldw_pwb, out);
}

// Round 16
// 231.322 us; speedup vs baseline: 1.6560x; 1.0004x over previous
//
#include <hip/hip_runtime.h>
#include <hip/hip_bf16.h>
#include <math.h>

#define HH 256
#define WW 256
#define NB 4
#define NC 128
#define C4 32

typedef __attribute__((ext_vector_type(8))) short short8v;
typedef __attribute__((ext_vector_type(4))) float float4v;
typedef unsigned short ushort_t;

__device__ __forceinline__ float gelu_f(float v) {
    return 0.5f * v * (1.0f + erff(v * 0.7071067811865476f));
}
__device__ __forceinline__ unsigned short f2bf(float x) {
    __hip_bfloat16 h = __float2bfloat16(x);
    return __builtin_bit_cast(unsigned short, h);
}
__device__ __forceinline__ float bf2f(unsigned short u) {
    return __uint_as_float(((unsigned)u) << 16);
}
__device__ __forceinline__ float bfe(short8v v, int j) {
    return bf2f((ushort_t)v[j]);
}

// ----------------------------------------------- K1: ln1g + prep merged ----
// Grid 1351: [0,1024) ln1g | [1024,1280) attxy | [1280,1282) attz |
// [1282,1346) convert_pw | [1346,1351) convert_ldwdw.
// prep blocks fill CUs alongside ln1g (no data deps between the two).
__global__ __launch_bounds__(256, 3) void ln1g_prep_kernel(
    const float* __restrict__ x,
    const float* __restrict__ n1w, const float* __restrict__ n1b,
    const float* __restrict__ dw_pww, const float* __restrict__ dw_pwb,
    ushort_t* __restrict__ g, float2* __restrict__ stats,
    const float* __restrict__ pxy,
    const float* __restrict__ cxy_dww, const float* __restrict__ cxy_dwb,
    const float* __restrict__ cxy_pww, const float* __restrict__ cxy_pwb,
    const float* __restrict__ pzx, const float* __restrict__ zx_dww,
    const float* __restrict__ zx_dwb, const float* __restrict__ zx_pww,
    const float* __restrict__ zx_pwb,
    const float* __restrict__ pzy, const float* __restrict__ zy_dww,
    const float* __restrict__ zy_dwb, const float* __restrict__ zy_pww,
    const float* __restrict__ zy_pwb,
    const float* __restrict__ ldw_pww, const float* __restrict__ ldw_dww,
    ushort_t* __restrict__ att_xy, float* __restrict__ att_zx,
    float* __restrict__ att_zy, ushort_t* __restrict__ pwb16,
    ushort_t* __restrict__ dwwT)
{
    const int bid = blockIdx.x;
    if (bid < 1024) {
        // ---- ln1g: thread = 1 px (R14-measured config) ----
        const int b = bid >> 8, h = bid & 255, w = threadIdx.x;
        const int pix = h * WW + w;
        const float* xp = x + (size_t)b * NC * 65536 + pix;

        float s1 = 0.f, s2 = 0.f;
        float x4v[32];
#pragma unroll
        for (int k = 0; k < 96; ++k) {
            float v = xp[(size_t)k * 65536];
            s1 += v; s2 += v * v;
        }
#pragma unroll
        for (int j = 0; j < 32; ++j) {
            float v = xp[(size_t)(96 + j) * 65536];
            x4v[j] = v; s1 += v; s2 += v * v;
        }
        const float m = s1 * (1.f / 128.f);
        const float r = rsqrtf(s2 * (1.f / 128.f) - m * m + 1e-6f);
        stats[(size_t)b * 65536 + pix] = float2{m, r};

#pragma unroll
        for (int j = 0; j < 32; ++j)
            x4v[j] = (x4v[j] - m) * r * n1w[96 + j] + n1b[96 + j];

        ushort_t* gp = g + ((size_t)b * 65536 + pix) * 32;
#pragma unroll
        for (int q = 0; q < 4; ++q) {
            short8v pk;
#pragma unroll
            for (int j = 0; j < 8; ++j) {
                const int co = q * 8 + j;
                float a = dw_pwb[co];
#pragma unroll
                for (int jj = 0; jj < 32; ++jj) a += dw_pww[co * 32 + jj] * x4v[jj];
                pk[j] = (short)f2bf(gelu_f(a));
            }
            *(short8v*)(gp + q * 8) = pk;
        }
        return;
    }
    if (bid >= 1282) {
        if (bid < 1346) {           // convert_pw
            int i = (bid - 1282) * 256 + threadIdx.x;
            pwb16[i] = f2bf(ldw_pww[i]);
        } else {                    // convert_ldwdw
            int i = (bid - 1346) * 256 + threadIdx.x;
            if (i < 1152) {
                int c = i / 9, tap = i % 9;
                dwwT[tap * 128 + c] = f2bf(ldw_dww[i]);
            }
        }
        return;
    }
    if (bid >= 1280) {              // attz: 2 blocks
        const bool sel = (bid != 1280);
        const float* params = sel ? pzy : pzx;
        const float* dww = sel ? zy_dww : zx_dww;
        const float* dwb = sel ? zy_dwb : zx_dwb;
        const float* pww = sel ? zy_pww : zx_pww;
        const float* pwb = sel ? zy_pwb : zx_pwb;
        float* att = sel ? att_zy : att_zx;
        const int pos = threadIdx.x;
        float gg[32];
#pragma unroll
        for (int c = 0; c < 32; ++c) {
            float a = dwb[c];
#pragma unroll
            for (int d = 0; d < 3; ++d) {
                int p = pos - 1 + d;
                if (p < 0 || p > 255) continue;
                float cz = p * (7.0f / 255.0f);
                int i0 = (int)floorf(cz); i0 = min(max(i0, 0), 7);
                int i1 = min(i0 + 1, 7);
                float f = cz - (float)i0;
                float pv = params[c * 8 + i0];
                pv += (params[c * 8 + i1] - pv) * f;
                a += dww[c * 3 + d] * pv;
            }
            gg[c] = gelu_f(a);
        }
#pragma unroll
        for (int co = 0; co < 32; ++co) {
            float a = pwb[co];
#pragma unroll
            for (int ci = 0; ci < 32; ++ci) a += pww[co * 32 + ci] * gg[ci];
            att[co * 256 + pos] = a;
        }
        return;
    }
    // ---- attxy: blocks [1024,1280) ----
    __shared__ float P[2048];
    __shared__ float DW[288];
    __shared__ float PW[1024];
    for (int i = threadIdx.x; i < 2048; i += 256) P[i] = pxy[i];
    for (int i = threadIdx.x; i < 288;  i += 256) DW[i] = cxy_dww[i];
    for (int i = threadIdx.x; i < 1024; i += 256) PW[i] = cxy_pww[i];
    __syncthreads();
    const int idx = (bid - 1024) * 256 + threadIdx.x;
    const int h = idx >> 8, w = idx & 255;

    int iy0[3], iy1[3], ix0[3], ix1[3];
    float fy[3], fx[3];
    bool vy[3], vx[3];
#pragma unroll
    for (int d = 0; d < 3; ++d) {
        int hh = h - 1 + d;
        vy[d] = (hh >= 0 && hh < HH);
        float cy = hh * (7.0f / 255.0f);
        int i0 = (int)floorf(cy); i0 = min(max(i0, 0), 7);
        iy0[d] = i0; iy1[d] = min(i0 + 1, 7); fy[d] = cy - (float)i0;
        int ww2 = w - 1 + d;
        vx[d] = (ww2 >= 0 && ww2 < WW);
        float cx = ww2 * (7.0f / 255.0f);
        int j0 = (int)floorf(cx); j0 = min(max(j0, 0), 7);
        ix0[d] = j0; ix1[d] = min(j0 + 1, 7); fx[d] = cx - (float)j0;
    }
    float gg[32];
#pragma unroll
    for (int c = 0; c < 32; ++c) {
        float a = cxy_dwb[c];
        const float* Pc = P + c * 64;
#pragma unroll
        for (int dy = 0; dy < 3; ++dy) {
            if (!vy[dy]) continue;
#pragma unroll
            for (int dx = 0; dx < 3; ++dx) {
                if (!vx[dx]) continue;
                float p00 = Pc[iy0[dy] * 8 + ix0[dx]];
                float p01 = Pc[iy0[dy] * 8 + ix1[dx]];
                float p10 = Pc[iy1[dy] * 8 + ix0[dx]];
                float p11 = Pc[iy1[dy] * 8 + ix1[dx]];
                float pt = p00 + (p01 - p00) * fx[dx];
                float pb = p10 + (p11 - p10) * fx[dx];
                float p  = pt + (pb - pt) * fy[dy];
                a += DW[c * 9 + dy * 3 + dx] * p;
            }
        }
        gg[c] = gelu_f(a);
    }
    ushort_t* ap = att_xy + (size_t)idx * 32;
#pragma unroll
    for (int q = 0; q < 4; ++q) {
        short8v pk;
#pragma unroll
        for (int j = 0; j < 8; ++j) {
            const int co = q * 8 + j;
            float a = cxy_pwb[co];
#pragma unroll
            for (int c = 0; c < 32; ++c) a += PW[co * 32 + c] * gg[c];
            pk[j] = (short)f2bf(a);
        }
        *(short8v*)(ap + q * 8) = pk;
    }
}

// ------------------------------------------------------------- K2: fuse ----
// R16: T14 issue-early/write-late — staging g loads into regs FIRST, then
// x/stats/att loads + normalize (all in flight together), then ds_write,
// barrier, dw. sv[] statically indexed (4x unrolled guard), dead by barrier.
__global__ __launch_bounds__(256) void fuse_kernel(
    const float* __restrict__ x, const float2* __restrict__ stats,
    const float* __restrict__ n1w, const float* __restrict__ n1b,
    const float* __restrict__ n2w, const float* __restrict__ n2b,
    const ushort_t* __restrict__ att_xy, const float* __restrict__ att_zx,
    const float* __restrict__ att_zy,
    const ushort_t* __restrict__ g,
    const float* __restrict__ dww, const float* __restrict__ dwb,
    ushort_t* __restrict__ z)
{
    __shared__ __align__(16) ushort_t gs[3][66][40];
    __shared__ float rs[4][64];
    __shared__ float rq[4][64];

    const int lid  = (blockIdx.x & 7) * 512 + (blockIdx.x >> 3);
    const int b     = lid >> 10;
    const int h     = (lid >> 2) & 255;
    const int strip = lid & 3;
    const int tid = threadIdx.x;
    const int q  = tid >> 6;
    const int px = tid & 63;
    const int w  = strip * 64 + px;
    const int pix = h * WW + w;
    const int w0g = strip * 64;

    // ---- phase 0: issue staging loads into registers ----
    short8v sv[4];
#pragma unroll
    for (int ii = 0; ii < 4; ++ii) {
        const int i = tid + ii * 256;
        if (i < 792) {
            const int row  = i / 264;
            const int rem  = i % 264;
            const int colc = rem >> 2;
            const int q8   = rem & 3;
            const int hy = min(max(h - 1 + row, 0), 255);
            const int cg = min(max(w0g + colc - 1, 0), 255);
            sv[ii] = *(const short8v*)(g + ((size_t)b * 65536 + hy * WW + cg) * 32 + q8 * 8);
        }
    }

    // ---- phase 1: x-branch loads + normalize (overlaps staging latency) ----
    const float2 st = stats[(size_t)b * 65536 + pix];
    const float m1 = st.x, r1 = st.y;

    float xn[4][8], u[4][8];
    {
        const short8v av = *(const short8v*)(att_xy + (size_t)pix * 32 + q * 8);
#pragma unroll
        for (int j = 0; j < 8; ++j) {
            const int c = q * 8 + j;
            float xv = x[((size_t)(b * NC + c)) * 65536 + pix];
            float v = (xv - m1) * r1 * n1w[c] + n1b[c];
            xn[0][j] = v; u[0][j] = v * bfe(av, j);
        }
    }
#pragma unroll
    for (int j = 0; j < 8; ++j) {
        const int c = 32 + q * 8 + j;
        float xv = x[((size_t)(b * NC + c)) * 65536 + pix];
        float v = (xv - m1) * r1 * n1w[c] + n1b[c];
        xn[1][j] = v; u[1][j] = v * att_zx[(c - 32) * 256 + h];
    }
#pragma unroll
    for (int j = 0; j < 8; ++j) {
        const int c = 64 + q * 8 + j;
        float xv = x[((size_t)(b * NC + c)) * 65536 + pix];
        float v = (xv - m1) * r1 * n1w[c] + n1b[c];
        xn[2][j] = v; u[2][j] = v * att_zy[(c - 64) * 256 + w];
    }
#pragma unroll
    for (int j = 0; j < 8; ++j) {
        const int c = 96 + q * 8 + j;
        float xv = x[((size_t)(b * NC + c)) * 65536 + pix];
        xn[3][j] = (xv - m1) * r1 * n1w[c] + n1b[c];
    }

    // ---- phase 2: write staged regs to LDS, barrier ----
#pragma unroll
    for (int ii = 0; ii < 4; ++ii) {
        const int i = tid + ii * 256;
        if (i < 792) {
            const int row  = i / 264;
            const int rem  = i % 264;
            const int colc = rem >> 2;
            const int q8   = rem & 3;
            *(short8v*)&gs[row][colc][q8 * 8] = sv[ii];
        }
    }
    __syncthreads();

    // ---- phase 3: dw3x3 over staged g ----
    {
        float a[8];
#pragma unroll
        for (int j = 0; j < 8; ++j) a[j] = dwb[q * 8 + j];
        const float ml = (w > 0) ? 1.f : 0.f;
        const float mr = (w < 255) ? 1.f : 0.f;
#pragma unroll
        for (int dy = -1; dy <= 1; ++dy) {
            int hy = h + dy;
            if (hy < 0 || hy > 255) continue;   // block-uniform
            const int rr = dy + 1;
            short8v gl = *(const short8v*)&gs[rr][px][q * 8];
            short8v gc = *(const short8v*)&gs[rr][px + 1][q * 8];
            short8v gv = *(const short8v*)&gs[rr][px + 2][q * 8];
            const int r0 = rr * 3;
#pragma unroll
            for (int j = 0; j < 8; ++j) {
                const float* wk = dww + (q * 8 + j) * 9 + r0;
                a[j] += (wk[0] * ml) * bfe(gl, j);
                a[j] += wk[1] * bfe(gc, j);
                a[j] += (wk[2] * mr) * bfe(gv, j);
            }
        }
#pragma unroll
        for (int j = 0; j < 8; ++j) u[3][j] = a[j];
    }
    // ---- LN2 stats ----
    float e1 = 0.f, e2 = 0.f;
#pragma unroll
    for (int br = 0; br < 4; ++br)
#pragma unroll
        for (int j = 0; j < 8; ++j) { e1 += u[br][j]; e2 += u[br][j] * u[br][j]; }
    rs[q][px] = e1; rq[q][px] = e2;
    __syncthreads();
    const float ssum = rs[0][px] + rs[1][px] + rs[2][px] + rs[3][px];
    const float qsum = rq[0][px] + rq[1][px] + rq[2][px] + rq[3][px];
    const float m2 = ssum * (1.f / 128.f);
    const float r2 = rsqrtf(qsum * (1.f / 128.f) - m2 * m2 + 1e-6f);
    ushort_t* zp = z + ((size_t)b * 65536 + pix) * 128;
#pragma unroll
    for (int br = 0; br < 4; ++br) {
        short8v pk;
#pragma unroll
        for (int j = 0; j < 8; ++j) {
            const int c = br * 32 + q * 8 + j;
            pk[j] = (short)f2bf((u[br][j] - m2) * r2 * n2w[c] + n2b[c] + xn[br][j]);
        }
        *(short8v*)(zp + br * 32 + q * 8) = pk;
    }
}

// --------------------------------------------------------------- ldw ----
// R7-exact (LOCKED, ~95 us measured R11/R13/R14/R15): launch_bounds (256,3).
// (256,5) forces VGPR 84->48, rematerializes z loads (FETCH 54->293MB,
// 115->223us, R10). Px mapping it*16+pr is wave-contiguous; R8/R9 remaps
// inflated traffic 3-5x. Do not modify without counter evidence.
__global__ __launch_bounds__(256, 3) void ldw_kernel(
    const ushort_t* __restrict__ z, const ushort_t* __restrict__ dwwT,
    const float* __restrict__ dwb, const ushort_t* __restrict__ wb16,
    const float* __restrict__ pwb, float* __restrict__ out)
{
    __shared__ __align__(16) ushort_t tl[64 * 128];

    const int lid  = (blockIdx.x & 7) * 512 + (blockIdx.x >> 3);
    const int b    = lid >> 10;
    const int h    = (lid >> 2) & 255;
    const int px0  = (lid & 3) * 64;
    const int tid  = threadIdx.x;

    {
        const int oc = tid & 15;
        const int pr = tid >> 4;
        short8v wt[9];
#pragma unroll
        for (int t = 0; t < 9; ++t)
            wt[t] = *(const short8v*)(dwwT + t * 128 + oc * 8);
        const float4 bd0 = *(const float4*)(dwb + oc * 8);
        const float4 bd1 = *(const float4*)(dwb + oc * 8 + 4);
        const float bdw[8] = {bd0.x, bd0.y, bd0.z, bd0.w, bd1.x, bd1.y, bd1.z, bd1.w};
        char* tlb = (char*)tl;
#pragma unroll
        for (int it = 0; it < 4; ++it) {
            const int px = it * 16 + pr;
            const int w  = px0 + px;
            const int wl = (w > 0) ? w - 1 : 0;
            const int wr2 = (w < 255) ? w + 1 : 255;
            const float ml = (w > 0) ? 1.f : 0.f;
            const float mr = (w < 255) ? 1.f : 0.f;
            float a[8];
#pragma unroll
            for (int j = 0; j < 8; ++j) a[j] = bdw[j];
#pragma unroll
            for (int dy = -1; dy <= 1; ++dy) {
                int hy = h + dy;
                if (hy < 0 || hy > 255) continue;
                const ushort_t* zr = z + ((size_t)b * 65536 + hy * WW) * 128 + oc * 8;
                short8v vl = *(const short8v*)(zr + (size_t)wl * 128);
                short8v vc = *(const short8v*)(zr + (size_t)w * 128);
                short8v vr = *(const short8v*)(zr + (size_t)wr2 * 128);
                const int r0 = (dy + 1) * 3;
#pragma unroll
                for (int j = 0; j < 8; ++j) {
                    a[j] += (bfe(wt[r0], j) * ml) * bfe(vl, j);
                    a[j] += bfe(wt[r0 + 1], j) * bfe(vc, j);
                    a[j] += (bfe(wt[r0 + 2], j) * mr) * bfe(vr, j);
                }
            }
            short8v pk;
#pragma unroll
            for (int j = 0; j < 8; ++j) pk[j] = (short)f2bf(gelu_f(a[j]));
            const int chunk = oc ^ (px & 15);
            *(short8v*)(tlb + px * 256 + chunk * 16) = pk;
        }
    }
    __syncthreads();

    const int lane = tid & 63;
    const int wv   = tid >> 6;
    const int l15  = lane & 15;
    const int l4   = lane >> 4;

    short8v afrag[2][4];
#pragma unroll
    for (int ct = 0; ct < 2; ++ct) {
        const int co = wv * 32 + ct * 16 + l15;
#pragma unroll
        for (int ks = 0; ks < 4; ++ks)
            afrag[ct][ks] = *(const short8v*)(wb16 + co * 128 + ks * 32 + l4 * 8);
    }
    float4v bias[2];
#pragma unroll
    for (int ct = 0; ct < 2; ++ct) {
        const float4 bv = *(const float4*)(pwb + wv * 32 + ct * 16 + l4 * 4);
        bias[ct] = float4v{bv.x, bv.y, bv.z, bv.w};
    }

    const char* tlb = (const char*)tl;
#pragma unroll
    for (int pt = 0; pt < 4; ++pt) {
        const int px = pt * 16 + l15;
        short8v bfrag[4];
#pragma unroll
        for (int ks = 0; ks < 4; ++ks) {
            const int chunk = (ks * 4 + l4) ^ (px & 15);
            bfrag[ks] = *(const short8v*)(tlb + px * 256 + chunk * 16);
        }
        float4v acc0 = bias[0];
        float4v acc1 = bias[1];
#pragma unroll
        for (int ks = 0; ks < 4; ++ks) {
            acc0 = __builtin_amdgcn_mfma_f32_16x16x32_bf16(afrag[0][ks], bfrag[ks], acc0, 0, 0, 0);
            acc1 = __builtin_amdgcn_mfma_f32_16x16x32_bf16(afrag[1][ks], bfrag[ks], acc1, 0, 0, 0);
        }
#pragma unroll
        for (int ct = 0; ct < 2; ++ct) {
            const int co = wv * 32 + ct * 16 + l4 * 4;
            float* op = out + ((size_t)(b * NC + co)) * 65536 + h * WW + px0 + pt * 16 + l15;
            const float4v av = ct ? acc1 : acc0;
#pragma unroll
            for (int r = 0; r < 4; ++r) op[(size_t)r * 65536] = av[r];
        }
    }
}

// ------------------------------------------------------------- launch ----
extern "C" void kernel_launch(void* const* d_in, const int* in_sizes, int n_in,
                              void* d_out, int out_size, void* d_ws, size_t ws_size,
                              hipStream_t stream)
{
    (void)in_sizes; (void)n_in; (void)out_size; (void)ws_size;
    const float* x       = (const float*)d_in[0];
    const float* n1w     = (const float*)d_in[1];
    const float* n1b     = (const float*)d_in[2];
    const float* pxy     = (const float*)d_in[3];
    const float* cxy_dww = (const float*)d_in[4];
    const float* cxy_dwb = (const float*)d_in[5];
    const float* cxy_pww = (const float*)d_in[6];
    const float* cxy_pwb = (const float*)d_in[7];
    const float* pzx     = (const float*)d_in[8];
    const float* czx_dww = (const float*)d_in[9];
    const float* czx_dwb = (const float*)d_in[10];
    const float* czx_pww = (const float*)d_in[11];
    const float* czx_pwb = (const float*)d_in[12];
    const float* pzy     = (const float*)d_in[13];
    const float* czy_dww = (const float*)d_in[14];
    const float* czy_dwb = (const float*)d_in[15];
    const float* czy_pww = (const float*)d_in[16];
    const float* czy_pwb = (const float*)d_in[17];
    const float* dw_pww  = (const float*)d_in[18];
    const float* dw_pwb  = (const float*)d_in[19];
    const float* dw_dww  = (const float*)d_in[20];
    const float* dw_dwb  = (const float*)d_in[21];
    const float* n2w     = (const float*)d_in[22];
    const float* n2b     = (const float*)d_in[23];
    const float* ldw_dww = (const float*)d_in[24];
    const float* ldw_dwb = (const float*)d_in[25];
    const float* ldw_pww = (const float*)d_in[26];
    const float* ldw_pwb = (const float*)d_in[27];
    float* out = (float*)d_out;
    char* ws   = (char*)d_ws;

    // layout (bytes): att_xy bf16 4MiB | att_zx/zy f32 64KB | pwb16 32KB |
    //                 dwwT 4KB | g 16MiB | z 64MiB | stats 2MiB
    ushort_t* att_xy = (ushort_t*)ws;
    float* att_zx = (float*)(ws + 4194304);
    float* att_zy = att_zx + 32 * 256;
    ushort_t* pwb16 = (ushort_t*)(att_zy + 32 * 256);
    ushort_t* dwwT  = pwb16 + 128 * 128;
    ushort_t* gbuf  = dwwT + 2048;
    ushort_t* zbuf  = gbuf + (size_t)4 * 65536 * 32;
    float2* stats   = (float2*)(zbuf + (size_t)4 * 65536 * 128);

    ln1g_prep_kernel<<<1351, 256, 0, stream>>>(
        x, n1w, n1b, dw_pww, dw_pwb, gbuf, stats,
        pxy, cxy_dww, cxy_dwb, cxy_pww, cxy_pwb,
        pzx, czx_dww, czx_dwb, czx_pww, czx_pwb,
        pzy, czy_dww, czy_dwb, czy_pww, czy_pwb,
        ldw_pww, ldw_dww,
        att_xy, att_zx, att_zy, pwb16, dwwT);
    fuse_kernel<<<4096, 256, 0, stream>>>(x, stats, n1w, n1b, n2w, n2b,
                                          att_xy, att_zx, att_zy,
                                          gbuf, dw_dww, dw_dwb, zbuf);
    ldw_kernel<<<4096, 256, 0, stream>>>(zbuf, dwwT, ldw_dwb, pwb16, ldw_pwb, out);
}